// Round 11
// baseline (801.930 us; speedup 1.0000x reference)
//
#include <hip/hip_runtime.h>
#include <math.h>

#define NN 100000
#define NN2 200000
#define NE 1200000
#define EMBD 100
#define HD 64
#define BT 4096
#define SCAN_B 196   // 196 * 1024 >= NN2
#define CSR_CAP 1536 // LDS-staged csr entries per block (avg 768, +27 sigma)

typedef __attribute__((ext_vector_type(8))) short short8;  // 8 bf16 (4 VGPRs)
typedef __attribute__((ext_vector_type(4))) float f32x4;   // MFMA C/D
typedef __attribute__((ext_vector_type(2))) float f32x2;   // fp8 pk-cvt result

__device__ __forceinline__ float sig1(float x) { return 1.f / (1.f + __expf(-x)); }
__device__ __forceinline__ float tanh1(float x) {
    x = fminf(fmaxf(x, -15.f), 15.f);
    float e = __expf(2.f * x);
    return (e - 1.f) / (e + 1.f);
}
__device__ __forceinline__ unsigned short f2b(float f) {
    unsigned u = __float_as_uint(f);
    u += 0x7fffu + ((u >> 16) & 1u);
    return (unsigned short)(u >> 16);
}
__device__ __forceinline__ unsigned short hi16(float f) {  // exact for fp8-sourced values
    return (unsigned short)(__float_as_uint(f) >> 16);
}
__device__ __forceinline__ unsigned packb(float lo, float hi) {
    return (unsigned)f2b(lo) | ((unsigned)f2b(hi) << 16);
}
// PERMUTED row layout for hb8 (fp8 state) and agg rows: position p holds feature
// (p&3)*16 + (p>>2); feature f lives at p = 4*(f&15) + (f>>4). Baked into wpack.
__device__ __forceinline__ unsigned pk8(float a, float b, float c, float d) {
    int w = 0;
    w = __builtin_amdgcn_cvt_pk_fp8_f32(a, b, w, false);
    w = __builtin_amdgcn_cvt_pk_fp8_f32(c, d, w, true);
    return (unsigned)w;
}
// 8 fp8 bytes -> 8 bf16 (exact: every e4m3 value is bf16-representable)
__device__ __forceinline__ short8 f8frag(uint2 u) {
    const f32x2 a0 = __builtin_amdgcn_cvt_pk_f32_fp8(u.x, false);
    const f32x2 a1 = __builtin_amdgcn_cvt_pk_f32_fp8(u.x, true);
    const f32x2 a2 = __builtin_amdgcn_cvt_pk_f32_fp8(u.y, false);
    const f32x2 a3 = __builtin_amdgcn_cvt_pk_f32_fp8(u.y, true);
    short8 r;
    r[0] = (short)hi16(a0.x); r[1] = (short)hi16(a0.y);
    r[2] = (short)hi16(a1.x); r[3] = (short)hi16(a1.y);
    r[4] = (short)hi16(a2.x); r[5] = (short)hi16(a2.y);
    r[6] = (short)hi16(a3.x); r[7] = (short)hi16(a3.y);
    return r;
}
// accumulate 16 fp8 features (one uint4) into acc[0..15], fp32, in-order
__device__ __forceinline__ void acc16(float* acc, uint4 u) {
    const f32x2 a0 = __builtin_amdgcn_cvt_pk_f32_fp8(u.x, false);
    const f32x2 a1 = __builtin_amdgcn_cvt_pk_f32_fp8(u.x, true);
    const f32x2 a2 = __builtin_amdgcn_cvt_pk_f32_fp8(u.y, false);
    const f32x2 a3 = __builtin_amdgcn_cvt_pk_f32_fp8(u.y, true);
    const f32x2 a4 = __builtin_amdgcn_cvt_pk_f32_fp8(u.z, false);
    const f32x2 a5 = __builtin_amdgcn_cvt_pk_f32_fp8(u.z, true);
    const f32x2 a6 = __builtin_amdgcn_cvt_pk_f32_fp8(u.w, false);
    const f32x2 a7 = __builtin_amdgcn_cvt_pk_f32_fp8(u.w, true);
    acc[0] += a0.x; acc[1] += a0.y; acc[2] += a1.x; acc[3] += a1.y;
    acc[4] += a2.x; acc[5] += a2.y; acc[6] += a3.x; acc[7] += a3.y;
    acc[8] += a4.x; acc[9] += a4.y; acc[10] += a5.x; acc[11] += a5.y;
    acc[12] += a6.x; acc[13] += a6.y; acc[14] += a7.x; acc[15] += a7.y;
}

// ---- precompute Wf[l] = Wm[l] @ Wih[l] (64x192), bf[l] = bm[l] @ Wih[l] (192) ----
__global__ __launch_bounds__(256) void fusew_kernel(
    const float* __restrict__ Wm0, const float* __restrict__ Wih0, const float* __restrict__ bm0,
    const float* __restrict__ Wm1, const float* __restrict__ Wih1, const float* __restrict__ bm1,
    float* __restrict__ Wf, float* __restrict__ bf) {
    extern __shared__ float lds[];
    float* wm_s = lds;          // 4096
    float* wih_s = lds + 4096;  // 12288
    const int l = blockIdx.x >> 3, slice = blockIdx.x & 7;
    const float* Wm = l ? Wm1 : Wm0;
    const float* Wih = l ? Wih1 : Wih0;
    const float* bm = l ? bm1 : bm0;
    for (int i = threadIdx.x; i < 4096; i += 256) wm_s[i] = Wm[i];
    for (int i = threadIdx.x; i < 12288; i += 256) wih_s[i] = Wih[i];
    __syncthreads();
    float* Wfl = Wf + l * 12288;
    float* bfl = bf + l * 192;
    const int o0 = slice * 1536;
    for (int o = o0 + threadIdx.x; o < o0 + 1536; o += 256) {
        int r = o / 192, c = o % 192;
        float s = 0.f;
        for (int k = 0; k < 64; ++k) s = fmaf(wm_s[r * 64 + k], wih_s[k * 192 + c], s);
        Wfl[o] = s;
    }
    const int c0 = slice * 24;
    for (int c = c0 + threadIdx.x; c < c0 + 24; c += 256) {
        float s = 0.f;
        for (int k = 0; k < 64; ++k) s = fmaf(bm[k], wih_s[k * 192 + c], s);
        bfl[c] = s;
    }
}

// ---- pack W' (128x256) into MFMA B-fragment order, bf16. Both halves permuted rows. ----
__global__ __launch_bounds__(64) void wpack_kernel(
    const float* __restrict__ Wf, const float* __restrict__ Whh0, const float* __restrict__ Whh1,
    unsigned short* __restrict__ Wpk) {
    const int b = blockIdx.x;  // 0..127
    const int l = b >> 6, frag = b & 63;
    const int nt = frag >> 2, kk = frag & 3;
    const int lane = threadIdx.x;
    const int n = nt * 16 + (lane & 15);
    const int g = n >> 6, j = n & 63;
    const int k0 = kk * 32 + (lane >> 4) * 8;
    const float* wf = Wf + l * 12288;
    const float* whh = l ? Whh1 : Whh0;
    unsigned short o[8];
#pragma unroll
    for (int jj = 0; jj < 8; ++jj) {
        const int k = k0 + jj;
        float v = 0.f;
        if (k < 64) {
            const int kp = (k & 3) * 16 + (k >> 2);
            if (g == 0) v = wf[kp * 192 + j];
            else if (g == 1) v = wf[kp * 192 + 64 + j];
            else if (g == 2) v = wf[kp * 192 + 128 + j];
        } else {
            const int kp = ((k - 64) & 3) * 16 + ((k - 64) >> 2);
            if (g == 0) v = whh[kp * 192 + j];
            else if (g == 1) v = whh[kp * 192 + 64 + j];
            else if (g == 3) v = whh[kp * 192 + 128 + j];
        }
        o[jj] = f2b(v);
    }
    *(uint4*)(Wpk + ((size_t)(l * 64 + frag) * 64 + lane) * 8) = *(const uint4*)o;
}

// ---- BLOCK-LEVEL fused hist + embed, PADDED counters. (R10: padding = null result,
// atomic wall is per-op fabric throughput; kept since harmless.)
// Atomic issued FIRST, rank stored LAST — embed body runs in the atomic shadow.
__global__ __launch_bounds__(256) void histemb_kernel(
    const int* __restrict__ adj0, const int* __restrict__ adj1, int* __restrict__ hcount,
    int* __restrict__ rank,
    const int* __restrict__ ind0, const int* __restrict__ ind1, const float* __restrict__ emb,
    const float* __restrict__ Wp, const float* __restrict__ bp, unsigned char* __restrict__ hb8) {
    __shared__ float et[4][EMBD][4];  // [wave][k][node]
    const int tid = threadIdx.x;

    // ---- hist role: issue the returning atomic now, consume at the very end ----
    int rsave = 0, esave = -1;
    if (tid < 192) {
        const int e = blockIdx.x * 192 + tid;
        const int tgt = (e < NE) ? adj0[2 * e + 1] : adj1[2 * (e - NE) + 1] + NN;
        rsave = atomicAdd(&hcount[tgt << 2], 1);
        esave = e;
    }

    // ---- embed role (unchanged body) ----
    const int w = tid >> 6;
    const int l = tid & 63;
    const int nodeBase = blockIdx.x * 16 + w * 4;  // global node id (graph-pure per block)
    for (int f = l; f < 100; f += 64) {
        const int n = f / 25, c = f % 25;
        const int gn = nodeBase + n;
        const int idx = (gn < NN) ? ind0[gn] : ind1[gn - NN];
        const float4 v = *(const float4*)(emb + (size_t)idx * EMBD + c * 4);
        et[w][c * 4 + 0][n] = v.x;
        et[w][c * 4 + 1][n] = v.y;
        et[w][c * 4 + 2][n] = v.z;
        et[w][c * 4 + 3][n] = v.w;
    }
    __syncthreads();
    float acc[4];
    acc[0] = bp[l]; acc[1] = acc[0]; acc[2] = acc[0]; acc[3] = acc[0];
#pragma unroll 5
    for (int k = 0; k < EMBD; ++k) {
        const float wv = Wp[k * 64 + l];
        const float4 ev = *(const float4*)&et[w][k][0];
        acc[0] = fmaf(ev.x, wv, acc[0]);
        acc[1] = fmaf(ev.y, wv, acc[1]);
        acc[2] = fmaf(ev.z, wv, acc[2]);
        acc[3] = fmaf(ev.w, wv, acc[3]);
    }
#pragma unroll
    for (int n = 0; n < 4; ++n) {
        const float v0 = __shfl(acc[n], l & 15);
        const float v1 = __shfl(acc[n], (l & 15) + 16);
        const float v2 = __shfl(acc[n], (l & 15) + 32);
        const float v3 = __shfl(acc[n], (l & 15) + 48);
        if (l < 16) ((unsigned*)(hb8 + (size_t)(nodeBase + n) * 64))[l] = pk8(v0, v1, v2, v3);
    }

    // ---- hist role epilogue: consume the atomic result ----
    if (esave >= 0) rank[esave] = rsave;
}

__global__ __launch_bounds__(256) void scan1_kernel(const int* __restrict__ hcount, int* __restrict__ bsum) {
    __shared__ int red[256];
    const int t = threadIdx.x, b = blockIdx.x;
    const int base = b * 1024;
    int s = 0;
    for (int i = t; i < 1024; i += 256) {
        const int idx = base + i;
        s += (idx < NN2) ? hcount[idx << 2] : 0;
    }
    red[t] = s;
    __syncthreads();
    for (int off = 128; off > 0; off >>= 1) {
        if (t < off) red[t] += red[t + off];
        __syncthreads();
    }
    if (t == 0) bsum[b] = red[0];
}

__global__ __launch_bounds__(256) void scan2_kernel(int* __restrict__ bsum) {
    __shared__ int s[256];
    const int t = threadIdx.x;
    const int v = (t < SCAN_B) ? bsum[t] : 0;
    s[t] = v;
    __syncthreads();
    for (int off = 1; off < 256; off <<= 1) {
        const int x = (t >= off) ? s[t - off] : 0;
        __syncthreads();
        s[t] += x;
        __syncthreads();
    }
    if (t < SCAN_B) bsum[t] = s[t] - v;  // exclusive
}

// ---- reads padded hcount, writes COMPACT exclusive-start rowptr + deg ----
__global__ __launch_bounds__(256) void scan3_kernel(const int* __restrict__ hcount,
                                                    int* __restrict__ rowptr,
                                                    const int* __restrict__ bsum,
                                                    float* __restrict__ deg) {
    __shared__ int red[256];
    const int t = threadIdx.x, b = blockIdx.x;
    const int i0 = b * 1024 + t * 4;
    int v[4];
#pragma unroll
    for (int j = 0; j < 4; ++j) v[j] = (i0 + j < NN2) ? hcount[(i0 + j) << 2] : 0;
    const int ts = v[0] + v[1] + v[2] + v[3];
    red[t] = ts;
    __syncthreads();
    for (int off = 1; off < 256; off <<= 1) {
        const int x = (t >= off) ? red[t - off] : 0;
        __syncthreads();
        red[t] += x;
        __syncthreads();
    }
    int pre = bsum[b] + red[t] - ts;
#pragma unroll
    for (int j = 0; j < 4; ++j) {
        if (i0 + j < NN2) {
            rowptr[i0 + j] = pre;  // EXCLUSIVE start (compact)
            deg[i0 + j] = (float)v[j];
            pre += v[j];
        }
    }
}

// ---- ATOMIC-FREE fill: slot = rowptr[tgt] (exclusive base) + rank[e]. ----
__global__ __launch_bounds__(256) void fill_kernel(
    const int* __restrict__ adj0, const int* __restrict__ adj1,
    const int* __restrict__ rowptr, const int* __restrict__ rank, int* __restrict__ csr) {
    const int e = blockIdx.x * 256 + threadIdx.x;
    int2 st;
    int off;
    if (e < NE) {
        st = ((const int2*)adj0)[e];
        off = 0;
    } else {
        st = ((const int2*)adj1)[e - NE];
        off = NN;
    }
    const int tgt = st.y + off;
    csr[rowptr[tgt] + rank[e]] = st.x + off;
}

// ---- FUSED aggregate + MFMA GRU, ping-pong state. Block = 64 nodes, 4 waves,
// ONE 16-row M-tile per wave. NEW (R11): the block's csr segment is CONTIGUOUS
// ([rowptr[nb0], rowptr[nb0+64])) — stage it into LDS with one coalesced pass, so
// the gather's critical path drops from two dependent global latencies (csr -> row)
// to one (row only; indices come from LDS). 8-edge unroll = 8 independent row loads
// in flight. Edge-visit order per thread unchanged -> identical numerics.
__global__ __launch_bounds__(256) void agru_kernel(
    const unsigned char* __restrict__ hsrc, unsigned char* __restrict__ hdst,
    const int* __restrict__ rowptr, const int* __restrict__ csr,
    const float* __restrict__ deg, const unsigned short* __restrict__ Wpk,
    const float* __restrict__ bf, const float* __restrict__ bih, const float* __restrict__ bhh) {
    extern __shared__ unsigned short ldsag[];  // 14336 B: 8K A-tile + 6K csr stage
    char* ldsA = (char*)ldsag;                 // [0, 8192)
    int* ldsI = (int*)((char*)ldsag + 8192);   // [8192, 14336): CSR_CAP ints
    const int tid = threadIdx.x;
    const int nb0 = blockIdx.x * 64;

    // ---- stage the block's contiguous csr segment (coalesced) ----
    const int e0 = rowptr[nb0];
    const int eEnd = (nb0 + 64 < NN2) ? rowptr[nb0 + 64] : 2 * NE;
    const int cnt = eEnd - e0;
    for (int i = tid; i < cnt && i < CSR_CAP; i += 256) ldsI[i] = csr[e0 + i];
    __syncthreads();

    // ---- phase 1: gather (4 threads/node, 16 features each; indices from LDS) ----
    {
        const int nl = tid >> 2;  // local node 0..63
        const int c = tid & 3;    // 16-feature (16 B fp8) chunk
        const int node = nb0 + nl;
        const int start = rowptr[node];
        const int end = (node + 1 < NN2) ? rowptr[node + 1] : 2 * NE;
        float acc[16];
#pragma unroll
        for (int j = 0; j < 16; ++j) acc[j] = 0.f;
        auto srcAt = [&](int e) {
            const int o = e - e0;
            return (o < CSR_CAP) ? ldsI[o] : csr[e];  // fallback never hit in practice
        };
        int e = start;
        for (; e + 7 < end; e += 8) {
            int s[8];
            uint4 u[8];
#pragma unroll
            for (int q = 0; q < 8; ++q) s[q] = srcAt(e + q);
#pragma unroll
            for (int q = 0; q < 8; ++q) u[q] = *(const uint4*)(hsrc + (size_t)s[q] * 64 + c * 16);
#pragma unroll
            for (int q = 0; q < 8; ++q) acc16(acc, u[q]);
        }
        for (; e < end; ++e) {
            const uint4 u = *(const uint4*)(hsrc + (size_t)srcAt(e) * 64 + c * 16);
            acc16(acc, u);
        }
        uint4 o0, o1;
        o0.x = packb(acc[0], acc[1]);
        o0.y = packb(acc[2], acc[3]);
        o0.z = packb(acc[4], acc[5]);
        o0.w = packb(acc[6], acc[7]);
        o1.x = packb(acc[8], acc[9]);
        o1.y = packb(acc[10], acc[11]);
        o1.z = packb(acc[12], acc[13]);
        o1.w = packb(acc[14], acc[15]);
        const int rowb = nl * 128 + c * 32;  // byte base within A-tile
        const int swz = (nl & 7) << 4;       // bank swizzle (16B-slot XOR within row)
        *(uint4*)(ldsA + ((rowb + 0) ^ swz)) = o0;
        *(uint4*)(ldsA + ((rowb + 16) ^ swz)) = o1;
    }

    // ---- phase 2: MFMA GRU (wave-local rows; no extra barrier needed) ----
    const int lane = tid & 63;
    const int w = tid >> 6;
    const int j0 = lane & 15, quad = lane >> 4;
    const int q8 = quad * 8;
    const int mbase = nb0 + w * 16;

    float cr[4], cz[4], cig[4], chg[4], vbfr[4], vbfz[4], vbfg[4];
#pragma unroll
    for (int c4 = 0; c4 < 4; ++c4) {
        const int col = c4 * 16 + j0;
        cr[c4] = bih[col] + bhh[col];
        cz[c4] = bih[64 + col] + bhh[64 + col];
        cig[c4] = bih[128 + col];
        chg[c4] = bhh[128 + col];
        vbfr[c4] = bf[col];
        vbfz[c4] = bf[64 + col];
        vbfg[c4] = bf[128 + col];
    }
    const short8* Wg8 = (const short8*)Wpk;  // global, L2-resident
    const int lr = w * 16 + j0;              // local A-row 0..63
    const int node0 = mbase + j0;
    auto ldA = [&](int half) -> short8 {
        const int byteoff = (lr * 128 + half * 64 + quad * 16) ^ ((lr & 7) << 4);
        return *(const short8*)(ldsA + byteoff);
    };

    short8 a[4];
    a[0] = ldA(0);
    a[1] = ldA(1);
    a[2] = f8frag(*(const uint2*)(hsrc + (size_t)node0 * 64 + q8));
    a[3] = f8frag(*(const uint2*)(hsrc + (size_t)node0 * 64 + 32 + q8));
    f32x4 acc[16];
#pragma unroll
    for (int i = 0; i < 16; ++i) acc[i] = (f32x4){0.f, 0.f, 0.f, 0.f};
#pragma unroll
    for (int nt = 0; nt < 16; ++nt) {
#pragma unroll
        for (int kk = 0; kk < 4; ++kk) {
            const short8 wv = Wg8[(nt * 4 + kk) * 64 + lane];
            acc[nt] = __builtin_amdgcn_mfma_f32_16x16x32_bf16(a[kk], wv, acc[nt], 0, 0, 0);
        }
    }

    // epilogue: rows mbase+quad*4 .. +4
#pragma unroll
    for (int reg = 0; reg < 4; ++reg) {
        const int node = mbase + quad * 4 + reg;
        const float dg = deg[node];
        const unsigned hu = *(const unsigned*)(hsrc + (size_t)node * 64 + j0 * 4);
        const f32x2 h01 = __builtin_amdgcn_cvt_pk_f32_fp8(hu, false);
        const f32x2 h23 = __builtin_amdgcn_cvt_pk_f32_fp8(hu, true);
        const float holdf[4] = {h01.x, h01.y, h23.x, h23.y};
        float hn[4];
#pragma unroll
        for (int c4 = 0; c4 < 4; ++c4) {
            const float rv = sig1(acc[c4][reg] + cr[c4] + dg * vbfr[c4]);
            const float zv = sig1(acc[4 + c4][reg] + cz[c4] + dg * vbfz[c4]);
            const float gi = acc[8 + c4][reg] + cig[c4] + dg * vbfg[c4];
            const float gh = acc[12 + c4][reg] + chg[c4];
            const float nv = tanh1(fmaf(rv, gh, gi));
            hn[c4] = (1.f - zv) * nv + zv * holdf[c4];
        }
        ((unsigned*)(hdst + (size_t)node * 64))[j0] = pk8(hn[0], hn[1], hn[2], hn[3]);
    }
}

// ---- aggX[p] for the 8192 (graph,b) prop pairs only ----
__global__ __launch_bounds__(256) void aggx_kernel(
    const int* __restrict__ prop0, const int* __restrict__ prop1,
    const int* __restrict__ rowptr, const int* __restrict__ csr,
    const unsigned char* __restrict__ hb8, unsigned short* __restrict__ aggX) {
    const int t = threadIdx.x;
    const int p = blockIdx.x * 64 + (t >> 2);
    const int c = t & 3;
    const int node = (p < BT) ? prop0[p] : NN + prop1[p - BT];
    const int start = rowptr[node];
    const int end = (node + 1 < NN2) ? rowptr[node + 1] : 2 * NE;
    float acc[16];
#pragma unroll
    for (int j = 0; j < 16; ++j) acc[j] = 0.f;
    for (int e = start; e < end; ++e) {
        const uint4 u = *(const uint4*)(hb8 + (size_t)csr[e] * 64 + c * 16);
        acc16(acc, u);
    }
    uint4 o0, o1;
    o0.x = packb(acc[0], acc[1]);
    o0.y = packb(acc[2], acc[3]);
    o0.z = packb(acc[4], acc[5]);
    o0.w = packb(acc[6], acc[7]);
    o1.x = packb(acc[8], acc[9]);
    o1.y = packb(acc[10], acc[11]);
    o1.z = packb(acc[12], acc[13]);
    o1.w = packb(acc[14], acc[15]);
    *(uint4*)(aggX + p * 64 + c * 16) = o0;
    *(uint4*)(aggX + p * 64 + c * 16 + 8) = o1;
}

// ---- Last-timestep GRU over the 8192 prop pairs only; writes X (fp32) directly. ----
__global__ __launch_bounds__(256) void grux_kernel(
    const int* __restrict__ prop0, const int* __restrict__ prop1,
    const unsigned char* __restrict__ hb8, const unsigned short* __restrict__ aggX,
    const float* __restrict__ deg, const unsigned short* __restrict__ Wpk,
    const float* __restrict__ bf, const float* __restrict__ bih, const float* __restrict__ bhh,
    float* __restrict__ X) {
    extern __shared__ unsigned short ldsW[];  // 64 KB
    {
        const uint4* src = (const uint4*)Wpk;
        uint4* dst = (uint4*)ldsW;
        for (int i = threadIdx.x; i < 4096; i += 256) dst[i] = src[i];
    }
    __syncthreads();
    const int lane = threadIdx.x & 63;
    const int j0 = lane & 15, quad = lane >> 4;
    const int q8 = quad * 8;
    float cr[4], cz[4], cig[4], chg[4], vbfr[4], vbfz[4], vbfg[4];
#pragma unroll
    for (int c4 = 0; c4 < 4; ++c4) {
        const int col = c4 * 16 + j0;
        cr[c4] = bih[col] + bhh[col];
        cz[c4] = bih[64 + col] + bhh[64 + col];
        cig[c4] = bih[128 + col];
        chg[c4] = bhh[128 + col];
        vbfr[c4] = bf[col];
        vbfz[c4] = bf[64 + col];
        vbfg[c4] = bf[128 + col];
    }
    const short8* ldsW8 = (const short8*)ldsW;
    const int gw = blockIdx.x * 4 + (threadIdx.x >> 6);  // 0..255, tile of 32 pairs

    auto mapnode = [&](int p) { return (p < BT) ? prop0[p] : NN + prop1[p - BT]; };

    auto epilogue = [&](const f32x4(&acc)[16], int pb) {
#pragma unroll
        for (int reg = 0; reg < 4; ++reg) {
            const int p = pb + reg;
            const int node = mapnode(p);
            const float dg = deg[node];
            const unsigned hu = *(const unsigned*)(hb8 + (size_t)node * 64 + j0 * 4);
            const f32x2 h01 = __builtin_amdgcn_cvt_pk_f32_fp8(hu, false);
            const f32x2 h23 = __builtin_amdgcn_cvt_pk_f32_fp8(hu, true);
            const float holdf[4] = {h01.x, h01.y, h23.x, h23.y};
            const int b = p & (BT - 1), g = p >> 12;
            float* xr = X + b * 128 + g * 64;
#pragma unroll
            for (int c4 = 0; c4 < 4; ++c4) {
                const int col = c4 * 16 + j0;
                const float rv = sig1(acc[c4][reg] + cr[c4] + dg * vbfr[c4]);
                const float zv = sig1(acc[4 + c4][reg] + cz[c4] + dg * vbfz[c4]);
                const float gi = acc[8 + c4][reg] + cig[c4] + dg * vbfg[c4];
                const float gh = acc[12 + c4][reg] + chg[c4];
                const float nv = tanh1(fmaf(rv, gh, gi));
                xr[col] = (1.f - zv) * nv + zv * holdf[c4];
            }
        }
    };

    const int mbase = gw * 32;
    const int p0 = mbase + j0, p1 = p0 + 16;
    const int node0 = mapnode(p0), node1 = mapnode(p1);
    short8 a[4], b[4];
    a[0] = *(const short8*)(aggX + p0 * 64 + q8);
    a[1] = *(const short8*)(aggX + p0 * 64 + 32 + q8);
    a[2] = f8frag(*(const uint2*)(hb8 + (size_t)node0 * 64 + q8));
    a[3] = f8frag(*(const uint2*)(hb8 + (size_t)node0 * 64 + 32 + q8));
    b[0] = *(const short8*)(aggX + p1 * 64 + q8);
    b[1] = *(const short8*)(aggX + p1 * 64 + 32 + q8);
    b[2] = f8frag(*(const uint2*)(hb8 + (size_t)node1 * 64 + q8));
    b[3] = f8frag(*(const uint2*)(hb8 + (size_t)node1 * 64 + 32 + q8));
    f32x4 acc0[16], acc1[16];
#pragma unroll
    for (int i = 0; i < 16; ++i) {
        acc0[i] = (f32x4){0.f, 0.f, 0.f, 0.f};
        acc1[i] = (f32x4){0.f, 0.f, 0.f, 0.f};
    }
#pragma unroll
    for (int nt = 0; nt < 16; ++nt) {
#pragma unroll
        for (int kk = 0; kk < 4; ++kk) {
            const short8 w = ldsW8[(nt * 4 + kk) * 64 + lane];
            acc0[nt] = __builtin_amdgcn_mfma_f32_16x16x32_bf16(a[kk], w, acc0[nt], 0, 0, 0);
            acc1[nt] = __builtin_amdgcn_mfma_f32_16x16x32_bf16(b[kk], w, acc1[nt], 0, 0, 0);
        }
    }
    epilogue(acc0, mbase + quad * 4);
    epilogue(acc1, mbase + 16 + quad * 4);
}

// ---- hidden = relu(X@W1+b1); z = hidden@W2+b2; out[b]=sigmoid(z); zbuf[b]=z ----
__global__ __launch_bounds__(256) void mlp_kernel(
    const float* __restrict__ X, const float* __restrict__ W1, const float* __restrict__ b1,
    const float* __restrict__ W2, const float* __restrict__ b2,
    float* __restrict__ out, float* __restrict__ zbuf) {
    const int b = blockIdx.x * 4 + (threadIdx.x >> 6);
    const int j = threadIdx.x & 63;
    const float* x = X + b * 128;
    float acc = b1[j];
#pragma unroll 4
    for (int k = 0; k < 128; ++k) acc = fmaf(x[k], W1[k * 64 + j], acc);
    float v = fmaxf(acc, 0.f) * W2[j];
#pragma unroll
    for (int off = 32; off > 0; off >>= 1) v += __shfl_down(v, off);
    if (j == 0) {
        const float z = v + b2[0];
        out[b] = 1.f / (1.f + expf(-z));
        zbuf[b] = z;
    }
}

// ---- loss = -mean(y*logsig(z) + (1-y)*logsig(-z)) -> out[BT] ----
__global__ __launch_bounds__(256) void loss_kernel(
    const float* __restrict__ zbuf, const int* __restrict__ labels, float* __restrict__ out) {
    __shared__ float red[256];
    const int t = threadIdx.x;
    float s = 0.f;
    for (int i = t; i < BT; i += 256) {
        const float z = zbuf[i];
        const float y = (float)labels[i];
        const float lsp = (z >= 0.f) ? -log1pf(expf(-z)) : (z - log1pf(expf(z)));
        const float lsn = lsp - z;
        s += y * lsp + (1.f - y) * lsn;
    }
    red[t] = s;
    __syncthreads();
    for (int off = 128; off > 0; off >>= 1) {
        if (t < off) red[t] += red[t + off];
        __syncthreads();
    }
    if (t == 0) out[BT] = -red[0] / (float)BT;
}

extern "C" void kernel_launch(void* const* d_in, const int* in_sizes, int n_in,
                              void* d_out, int out_size, void* d_ws, size_t ws_size,
                              hipStream_t stream) {
    char* ws = (char*)d_ws;
    // hb8B aliases the old aggb region (aggb no longer exists).
    unsigned char* hb8B = (unsigned char*)(ws);               // 12,800,000 B
    unsigned char* hb8A = (unsigned char*)(ws + 25600000);    // 12,800,000 B
    float* deg = (float*)(ws + 38400000);                     // 800,000 B
    float* Wf = (float*)(ws + 39200000);                      // 98,304 B
    float* bf = (float*)(ws + 39298304);                      // 1,536 B
    int* rowptr = (int*)(ws + 39299840);                      // 800,000 B (compact)
    int* csr = (int*)(ws + 40099840);                         // 9,600,000 B
    int* bsum = (int*)(ws + 49699840);                        // 1,024 B
    unsigned short* Wpk = (unsigned short*)(ws + 49700864);   // 131,072 B
    unsigned short* aggX = (unsigned short*)(ws + 49831936);  // 1,048,576 B
    // rank + padded hcount alias the hb8A region (dead until agru step 0; both are
    // fully consumed by fill/scan3, which run before agru).
    int* rank = (int*)(ws + 25600000);                        // 9,600,000 B (alias hb8A)
    int* hcount = (int*)(ws + 35200000);                      // 3,200,000 B (alias hb8A tail)
    // X/zbuf alias hb8B region (dead when grux runs; grux reads hb8A + aggX only).
    float* X = (float*)(ws);
    float* zbuf = (float*)(ws + 2097152);
    float* out = (float*)d_out;

    const float* emb_table = (const float*)d_in[7];
    const float* Wp = (const float*)d_in[8];
    const float* bp = (const float*)d_in[9];
    const int* prop0 = (const int*)d_in[4];
    const int* prop1 = (const int*)d_in[5];

    fusew_kernel<<<16, 256, 65536, stream>>>(
        (const float*)d_in[10], (const float*)d_in[12], (const float*)d_in[11],
        (const float*)d_in[16], (const float*)d_in[18], (const float*)d_in[17], Wf, bf);
    wpack_kernel<<<128, 64, 0, stream>>>(Wf, (const float*)d_in[13], (const float*)d_in[19], Wpk);

    // ---- block-level fused hist + embed (padded counters) ----
    hipMemsetAsync(hcount, 0, (size_t)NN2 * 16, stream);
    histemb_kernel<<<NN2 / 16, 256, 0, stream>>>(
        (const int*)d_in[2], (const int*)d_in[3], hcount, rank,
        (const int*)d_in[0], (const int*)d_in[1], emb_table, Wp, bp, hb8B);
    scan1_kernel<<<SCAN_B, 256, 0, stream>>>(hcount, bsum);
    scan2_kernel<<<1, 256, 0, stream>>>(bsum);
    scan3_kernel<<<SCAN_B, 256, 0, stream>>>(hcount, rowptr, bsum, deg);
    fill_kernel<<<2 * NE / 256, 256, 0, stream>>>((const int*)d_in[2], (const int*)d_in[3], rowptr,
                                                  rank, csr);

    // ---- 5 fused agg+GRU steps (l0:ts0-2, l1:ts0-1), ping-pong B->A->B->A->B->A ----
    for (int s = 0; s < 5; ++s) {
        const int l = (s < 3) ? 0 : 1;
        const unsigned char* src = (s & 1) ? hb8A : hb8B;
        unsigned char* dst = (s & 1) ? hb8B : hb8A;
        const float* bih = (const float*)d_in[14 + 6 * l];
        const float* bhh = (const float*)d_in[15 + 6 * l];
        agru_kernel<<<NN2 / 64, 256, 14336, stream>>>(
            src, dst, rowptr, csr, deg, Wpk + l * 32768, bf + l * 192, bih, bhh);
    }

    // ---- last timestep (l=1, ts=2), pruned to the 8192 prop pairs; state is in hb8A ----
    {
        const float* bih = (const float*)d_in[20];
        const float* bhh = (const float*)d_in[21];
        aggx_kernel<<<2 * BT / 64, 256, 0, stream>>>(prop0, prop1, rowptr, csr, hb8A, aggX);
        grux_kernel<<<64, 256, 65536, stream>>>(prop0, prop1, hb8A, aggX, deg, Wpk + 32768,
                                                bf + 192, bih, bhh, X);
    }

    mlp_kernel<<<BT / 4, 256, 0, stream>>>(X, (const float*)d_in[22], (const float*)d_in[23],
                                           (const float*)d_in[24], (const float*)d_in[25], out, zbuf);
    loss_kernel<<<1, 256, 0, stream>>>(zbuf, (const int*)d_in[6], out);
}

// Round 13
// 768.161 us; speedup vs baseline: 1.0440x; 1.0440x over previous
//
#include <hip/hip_runtime.h>
#include <math.h>

#define NN 100000
#define NN2 200000
#define NE 1200000
#define EMBD 100
#define HD 64
#define BT 4096
#define SCAN_B 196  // 196 * 1024 >= NN2

typedef __attribute__((ext_vector_type(8))) short short8;  // 8 bf16 (4 VGPRs)
typedef __attribute__((ext_vector_type(4))) float f32x4;   // MFMA C/D
typedef __attribute__((ext_vector_type(2))) float f32x2;   // fp8 pk-cvt result

__device__ __forceinline__ float sig1(float x) { return 1.f / (1.f + __expf(-x)); }
__device__ __forceinline__ float tanh1(float x) {
    x = fminf(fmaxf(x, -15.f), 15.f);
    float e = __expf(2.f * x);
    return (e - 1.f) / (e + 1.f);
}
__device__ __forceinline__ unsigned short f2b(float f) {
    unsigned u = __float_as_uint(f);
    u += 0x7fffu + ((u >> 16) & 1u);
    return (unsigned short)(u >> 16);
}
__device__ __forceinline__ unsigned short hi16(float f) {  // exact for fp8-sourced values
    return (unsigned short)(__float_as_uint(f) >> 16);
}
__device__ __forceinline__ unsigned packb(float lo, float hi) {
    return (unsigned)f2b(lo) | ((unsigned)f2b(hi) << 16);
}
// PERMUTED row layout for hb8 (fp8 state) and agg rows: position p holds feature
// (p&3)*16 + (p>>2); feature f lives at p = 4*(f&15) + (f>>4). Baked into wpack.
__device__ __forceinline__ unsigned pk8(float a, float b, float c, float d) {
    int w = 0;
    w = __builtin_amdgcn_cvt_pk_fp8_f32(a, b, w, false);
    w = __builtin_amdgcn_cvt_pk_fp8_f32(c, d, w, true);
    return (unsigned)w;
}
// 8 fp8 bytes -> 8 bf16 (exact: every e4m3 value is bf16-representable)
__device__ __forceinline__ short8 f8frag(uint2 u) {
    const f32x2 a0 = __builtin_amdgcn_cvt_pk_f32_fp8(u.x, false);
    const f32x2 a1 = __builtin_amdgcn_cvt_pk_f32_fp8(u.x, true);
    const f32x2 a2 = __builtin_amdgcn_cvt_pk_f32_fp8(u.y, false);
    const f32x2 a3 = __builtin_amdgcn_cvt_pk_f32_fp8(u.y, true);
    short8 r;
    r[0] = (short)hi16(a0.x); r[1] = (short)hi16(a0.y);
    r[2] = (short)hi16(a1.x); r[3] = (short)hi16(a1.y);
    r[4] = (short)hi16(a2.x); r[5] = (short)hi16(a2.y);
    r[6] = (short)hi16(a3.x); r[7] = (short)hi16(a3.y);
    return r;
}
// accumulate 16 fp8 features (one uint4) into acc[0..15], fp32, in-order
__device__ __forceinline__ void acc16(float* acc, uint4 u) {
    const f32x2 a0 = __builtin_amdgcn_cvt_pk_f32_fp8(u.x, false);
    const f32x2 a1 = __builtin_amdgcn_cvt_pk_f32_fp8(u.x, true);
    const f32x2 a2 = __builtin_amdgcn_cvt_pk_f32_fp8(u.y, false);
    const f32x2 a3 = __builtin_amdgcn_cvt_pk_f32_fp8(u.y, true);
    const f32x2 a4 = __builtin_amdgcn_cvt_pk_f32_fp8(u.z, false);
    const f32x2 a5 = __builtin_amdgcn_cvt_pk_f32_fp8(u.z, true);
    const f32x2 a6 = __builtin_amdgcn_cvt_pk_f32_fp8(u.w, false);
    const f32x2 a7 = __builtin_amdgcn_cvt_pk_f32_fp8(u.w, true);
    acc[0] += a0.x; acc[1] += a0.y; acc[2] += a1.x; acc[3] += a1.y;
    acc[4] += a2.x; acc[5] += a2.y; acc[6] += a3.x; acc[7] += a3.y;
    acc[8] += a4.x; acc[9] += a4.y; acc[10] += a5.x; acc[11] += a5.y;
    acc[12] += a6.x; acc[13] += a6.y; acc[14] += a7.x; acc[15] += a7.y;
}

// ---- precompute Wf[l] = Wm[l] @ Wih[l] (64x192), bf[l] = bm[l] @ Wih[l] (192) ----
__global__ __launch_bounds__(256) void fusew_kernel(
    const float* __restrict__ Wm0, const float* __restrict__ Wih0, const float* __restrict__ bm0,
    const float* __restrict__ Wm1, const float* __restrict__ Wih1, const float* __restrict__ bm1,
    float* __restrict__ Wf, float* __restrict__ bf) {
    extern __shared__ float lds[];
    float* wm_s = lds;          // 4096
    float* wih_s = lds + 4096;  // 12288
    const int l = blockIdx.x >> 3, slice = blockIdx.x & 7;
    const float* Wm = l ? Wm1 : Wm0;
    const float* Wih = l ? Wih1 : Wih0;
    const float* bm = l ? bm1 : bm0;
    for (int i = threadIdx.x; i < 4096; i += 256) wm_s[i] = Wm[i];
    for (int i = threadIdx.x; i < 12288; i += 256) wih_s[i] = Wih[i];
    __syncthreads();
    float* Wfl = Wf + l * 12288;
    float* bfl = bf + l * 192;
    const int o0 = slice * 1536;
    for (int o = o0 + threadIdx.x; o < o0 + 1536; o += 256) {
        int r = o / 192, c = o % 192;
        float s = 0.f;
        for (int k = 0; k < 64; ++k) s = fmaf(wm_s[r * 64 + k], wih_s[k * 192 + c], s);
        Wfl[o] = s;
    }
    const int c0 = slice * 24;
    for (int c = c0 + threadIdx.x; c < c0 + 24; c += 256) {
        float s = 0.f;
        for (int k = 0; k < 64; ++k) s = fmaf(bm[k], wih_s[k * 192 + c], s);
        bfl[c] = s;
    }
}

// ---- pack W' (128x256) into MFMA B-fragment order, bf16. Both halves permuted rows. ----
__global__ __launch_bounds__(64) void wpack_kernel(
    const float* __restrict__ Wf, const float* __restrict__ Whh0, const float* __restrict__ Whh1,
    unsigned short* __restrict__ Wpk) {
    const int b = blockIdx.x;  // 0..127
    const int l = b >> 6, frag = b & 63;
    const int nt = frag >> 2, kk = frag & 3;
    const int lane = threadIdx.x;
    const int n = nt * 16 + (lane & 15);
    const int g = n >> 6, j = n & 63;
    const int k0 = kk * 32 + (lane >> 4) * 8;
    const float* wf = Wf + l * 12288;
    const float* whh = l ? Whh1 : Whh0;
    unsigned short o[8];
#pragma unroll
    for (int jj = 0; jj < 8; ++jj) {
        const int k = k0 + jj;
        float v = 0.f;
        if (k < 64) {
            const int kp = (k & 3) * 16 + (k >> 2);
            if (g == 0) v = wf[kp * 192 + j];
            else if (g == 1) v = wf[kp * 192 + 64 + j];
            else if (g == 2) v = wf[kp * 192 + 128 + j];
        } else {
            const int kp = ((k - 64) & 3) * 16 + ((k - 64) >> 2);
            if (g == 0) v = whh[kp * 192 + j];
            else if (g == 1) v = whh[kp * 192 + 64 + j];
            else if (g == 3) v = whh[kp * 192 + 128 + j];
        }
        o[jj] = f2b(v);
    }
    *(uint4*)(Wpk + ((size_t)(l * 64 + frag) * 64 + lane) * 8) = *(const uint4*)o;
}

// ---- BLOCK-LEVEL fused hist + embed, PADDED counters. (R10: padding = null result,
// atomic wall is per-op fabric throughput; kept since harmless.)
// Atomic issued FIRST, rank stored LAST — embed body runs in the atomic shadow.
__global__ __launch_bounds__(256) void histemb_kernel(
    const int* __restrict__ adj0, const int* __restrict__ adj1, int* __restrict__ hcount,
    int* __restrict__ rank,
    const int* __restrict__ ind0, const int* __restrict__ ind1, const float* __restrict__ emb,
    const float* __restrict__ Wp, const float* __restrict__ bp, unsigned char* __restrict__ hb8) {
    __shared__ float et[4][EMBD][4];  // [wave][k][node]
    const int tid = threadIdx.x;

    // ---- hist role: issue the returning atomic now, consume at the very end ----
    int rsave = 0, esave = -1;
    if (tid < 192) {
        const int e = blockIdx.x * 192 + tid;
        const int tgt = (e < NE) ? adj0[2 * e + 1] : adj1[2 * (e - NE) + 1] + NN;
        rsave = atomicAdd(&hcount[tgt << 2], 1);
        esave = e;
    }

    // ---- embed role (unchanged body) ----
    const int w = tid >> 6;
    const int l = tid & 63;
    const int nodeBase = blockIdx.x * 16 + w * 4;  // global node id (graph-pure per block)
    for (int f = l; f < 100; f += 64) {
        const int n = f / 25, c = f % 25;
        const int gn = nodeBase + n;
        const int idx = (gn < NN) ? ind0[gn] : ind1[gn - NN];
        const float4 v = *(const float4*)(emb + (size_t)idx * EMBD + c * 4);
        et[w][c * 4 + 0][n] = v.x;
        et[w][c * 4 + 1][n] = v.y;
        et[w][c * 4 + 2][n] = v.z;
        et[w][c * 4 + 3][n] = v.w;
    }
    __syncthreads();
    float acc[4];
    acc[0] = bp[l]; acc[1] = acc[0]; acc[2] = acc[0]; acc[3] = acc[0];
#pragma unroll 5
    for (int k = 0; k < EMBD; ++k) {
        const float wv = Wp[k * 64 + l];
        const float4 ev = *(const float4*)&et[w][k][0];
        acc[0] = fmaf(ev.x, wv, acc[0]);
        acc[1] = fmaf(ev.y, wv, acc[1]);
        acc[2] = fmaf(ev.z, wv, acc[2]);
        acc[3] = fmaf(ev.w, wv, acc[3]);
    }
#pragma unroll
    for (int n = 0; n < 4; ++n) {
        const float v0 = __shfl(acc[n], l & 15);
        const float v1 = __shfl(acc[n], (l & 15) + 16);
        const float v2 = __shfl(acc[n], (l & 15) + 32);
        const float v3 = __shfl(acc[n], (l & 15) + 48);
        if (l < 16) ((unsigned*)(hb8 + (size_t)(nodeBase + n) * 64))[l] = pk8(v0, v1, v2, v3);
    }

    // ---- hist role epilogue: consume the atomic result ----
    if (esave >= 0) rank[esave] = rsave;
}

__global__ __launch_bounds__(256) void scan1_kernel(const int* __restrict__ hcount, int* __restrict__ bsum) {
    __shared__ int red[256];
    const int t = threadIdx.x, b = blockIdx.x;
    const int base = b * 1024;
    int s = 0;
    for (int i = t; i < 1024; i += 256) {
        const int idx = base + i;
        s += (idx < NN2) ? hcount[idx << 2] : 0;
    }
    red[t] = s;
    __syncthreads();
    for (int off = 128; off > 0; off >>= 1) {
        if (t < off) red[t] += red[t + off];
        __syncthreads();
    }
    if (t == 0) bsum[b] = red[0];
}

__global__ __launch_bounds__(256) void scan2_kernel(int* __restrict__ bsum) {
    __shared__ int s[256];
    const int t = threadIdx.x;
    const int v = (t < SCAN_B) ? bsum[t] : 0;
    s[t] = v;
    __syncthreads();
    for (int off = 1; off < 256; off <<= 1) {
        const int x = (t >= off) ? s[t - off] : 0;
        __syncthreads();
        s[t] += x;
        __syncthreads();
    }
    if (t < SCAN_B) bsum[t] = s[t] - v;  // exclusive
}

// ---- reads padded hcount, writes COMPACT exclusive-start rowptr + deg ----
__global__ __launch_bounds__(256) void scan3_kernel(const int* __restrict__ hcount,
                                                    int* __restrict__ rowptr,
                                                    const int* __restrict__ bsum,
                                                    float* __restrict__ deg) {
    __shared__ int red[256];
    const int t = threadIdx.x, b = blockIdx.x;
    const int i0 = b * 1024 + t * 4;
    int v[4];
#pragma unroll
    for (int j = 0; j < 4; ++j) v[j] = (i0 + j < NN2) ? hcount[(i0 + j) << 2] : 0;
    const int ts = v[0] + v[1] + v[2] + v[3];
    red[t] = ts;
    __syncthreads();
    for (int off = 1; off < 256; off <<= 1) {
        const int x = (t >= off) ? red[t - off] : 0;
        __syncthreads();
        red[t] += x;
        __syncthreads();
    }
    int pre = bsum[b] + red[t] - ts;
#pragma unroll
    for (int j = 0; j < 4; ++j) {
        if (i0 + j < NN2) {
            rowptr[i0 + j] = pre;  // EXCLUSIVE start (compact)
            deg[i0 + j] = (float)v[j];
            pre += v[j];
        }
    }
}

// ---- ATOMIC-FREE fill: slot = rowptr[tgt] (exclusive base) + rank[e]. ----
__global__ __launch_bounds__(256) void fill_kernel(
    const int* __restrict__ adj0, const int* __restrict__ adj1,
    const int* __restrict__ rowptr, const int* __restrict__ rank, int* __restrict__ csr) {
    const int e = blockIdx.x * 256 + threadIdx.x;
    int2 st;
    int off;
    if (e < NE) {
        st = ((const int2*)adj0)[e];
        off = 0;
    } else {
        st = ((const int2*)adj1)[e - NE];
        off = NN;
    }
    const int tgt = st.y + off;
    csr[rowptr[tgt] + rank[e]] = st.x + off;
}

// ---- FUSED aggregate + MFMA GRU, ping-pong state. Block = 64 nodes, 4 waves.
// Gather: EXACT R10 body (4 thr/node, 4-edge unroll, direct csr, NO barrier).
// Phase 2 (R12/R13): c4-SPLIT — 4 passes of {r,z,ig,hg} with 4 accumulators each
// (16 regs) instead of acc[16] (64 regs). fp8 output word built incrementally with
// LITERAL-constant cvt_pk word selects (builtin requires constant int — R12 lesson).
// Same MFMA count/addresses, same per-accumulator op order -> identical numerics.
__global__ __launch_bounds__(256) void agru_kernel(
    const unsigned char* __restrict__ hsrc, unsigned char* __restrict__ hdst,
    const int* __restrict__ rowptr, const int* __restrict__ csr,
    const float* __restrict__ deg, const unsigned short* __restrict__ Wpk,
    const float* __restrict__ bf, const float* __restrict__ bih, const float* __restrict__ bhh) {
    extern __shared__ unsigned short ldsag[];  // 8192 B: 64-row A-tile
    char* ldsA = (char*)ldsag;
    const int tid = threadIdx.x;
    const int nb0 = blockIdx.x * 64;

    // ---- phase 1: gather (4 threads/node, 16 features each) ----
    {
        const int nl = tid >> 2;  // local node 0..63
        const int c = tid & 3;    // 16-feature (16 B fp8) chunk
        const int node = nb0 + nl;
        const int start = rowptr[node];
        const int end = (node + 1 < NN2) ? rowptr[node + 1] : 2 * NE;
        float acc[16];
#pragma unroll
        for (int j = 0; j < 16; ++j) acc[j] = 0.f;
        int e = start;
        for (; e + 3 < end; e += 4) {
            int s[4];
            uint4 u[4];
#pragma unroll
            for (int q = 0; q < 4; ++q) s[q] = csr[e + q];
#pragma unroll
            for (int q = 0; q < 4; ++q) u[q] = *(const uint4*)(hsrc + (size_t)s[q] * 64 + c * 16);
#pragma unroll
            for (int q = 0; q < 4; ++q) acc16(acc, u[q]);
        }
        for (; e < end; ++e) {
            const uint4 u = *(const uint4*)(hsrc + (size_t)csr[e] * 64 + c * 16);
            acc16(acc, u);
        }
        uint4 o0, o1;
        o0.x = packb(acc[0], acc[1]);
        o0.y = packb(acc[2], acc[3]);
        o0.z = packb(acc[4], acc[5]);
        o0.w = packb(acc[6], acc[7]);
        o1.x = packb(acc[8], acc[9]);
        o1.y = packb(acc[10], acc[11]);
        o1.z = packb(acc[12], acc[13]);
        o1.w = packb(acc[14], acc[15]);
        const int rowb = nl * 128 + c * 32;  // byte base within A-tile
        const int swz = (nl & 7) << 4;       // bank swizzle (16B-slot XOR within row)
        *(uint4*)(ldsA + ((rowb + 0) ^ swz)) = o0;
        *(uint4*)(ldsA + ((rowb + 16) ^ swz)) = o1;
    }

    // ---- phase 2: MFMA GRU, c4-split (wave-local rows; no block barrier needed) ----
    const int lane = tid & 63;
    const int w = tid >> 6;
    const int j0 = lane & 15, quad = lane >> 4;
    const int q8 = quad * 8;
    const int mbase = nb0 + w * 16;

    const short8* Wg8 = (const short8*)Wpk;  // global, L2-resident
    const int lr = w * 16 + j0;              // local A-row 0..63
    const int node0 = mbase + j0;
    auto ldA = [&](int half) -> short8 {
        const int byteoff = (lr * 128 + half * 64 + quad * 16) ^ ((lr & 7) << 4);
        return *(const short8*)(ldsA + byteoff);
    };

    short8 a[4];
    a[0] = ldA(0);
    a[1] = ldA(1);
    a[2] = f8frag(*(const uint2*)(hsrc + (size_t)node0 * 64 + q8));
    a[3] = f8frag(*(const uint2*)(hsrc + (size_t)node0 * 64 + 32 + q8));

    // preload old-state words + degrees for the 4 epilogue rows
    unsigned hu[4];
    float dgv[4];
#pragma unroll
    for (int reg = 0; reg < 4; ++reg) {
        const int node = mbase + quad * 4 + reg;
        hu[reg] = *(const unsigned*)(hsrc + (size_t)node * 64 + j0 * 4);
        dgv[reg] = deg[node];
    }

    int wpk[4] = {0, 0, 0, 0};  // packed fp8 output words (built incrementally)
    float hnPrev[4];            // pending even-c4 value per row

#pragma unroll
    for (int c4 = 0; c4 < 4; ++c4) {
        const int col = c4 * 16 + j0;
        const float crv = bih[col] + bhh[col];
        const float czv = bih[64 + col] + bhh[64 + col];
        const float cigv = bih[128 + col];
        const float chgv = bhh[128 + col];
        const float bfr = bf[col];
        const float bfz = bf[64 + col];
        const float bfg = bf[128 + col];
        f32x4 ar = (f32x4){0.f, 0.f, 0.f, 0.f};
        f32x4 az = (f32x4){0.f, 0.f, 0.f, 0.f};
        f32x4 ai = (f32x4){0.f, 0.f, 0.f, 0.f};
        f32x4 ah = (f32x4){0.f, 0.f, 0.f, 0.f};
#pragma unroll
        for (int kk = 0; kk < 4; ++kk) {
            ar = __builtin_amdgcn_mfma_f32_16x16x32_bf16(a[kk], Wg8[(c4 * 4 + kk) * 64 + lane], ar, 0, 0, 0);
            az = __builtin_amdgcn_mfma_f32_16x16x32_bf16(a[kk], Wg8[((4 + c4) * 4 + kk) * 64 + lane], az, 0, 0, 0);
            ai = __builtin_amdgcn_mfma_f32_16x16x32_bf16(a[kk], Wg8[((8 + c4) * 4 + kk) * 64 + lane], ai, 0, 0, 0);
            ah = __builtin_amdgcn_mfma_f32_16x16x32_bf16(a[kk], Wg8[((12 + c4) * 4 + kk) * 64 + lane], ah, 0, 0, 0);
        }
#pragma unroll
        for (int reg = 0; reg < 4; ++reg) {
            const float dg = dgv[reg];
            // builtin word-selects must be LITERAL constants; branches fold under unroll
            f32x2 hpair;
            if (c4 < 2) hpair = __builtin_amdgcn_cvt_pk_f32_fp8(hu[reg], false);
            else hpair = __builtin_amdgcn_cvt_pk_f32_fp8(hu[reg], true);
            const float hold = (c4 & 1) ? hpair.y : hpair.x;
            const float rv = sig1(ar[reg] + crv + dg * bfr);
            const float zv = sig1(az[reg] + czv + dg * bfz);
            const float gi = ai[reg] + cigv + dg * bfg;
            const float gh = ah[reg] + chgv;
            const float nv = tanh1(fmaf(rv, gh, gi));
            const float hn = (1.f - zv) * nv + zv * hold;
            if ((c4 & 1) == 0) {
                hnPrev[reg] = hn;
            } else if (c4 == 1) {
                wpk[reg] = __builtin_amdgcn_cvt_pk_fp8_f32(hnPrev[reg], hn, wpk[reg], false);
            } else {
                wpk[reg] = __builtin_amdgcn_cvt_pk_fp8_f32(hnPrev[reg], hn, wpk[reg], true);
            }
        }
    }
#pragma unroll
    for (int reg = 0; reg < 4; ++reg) {
        const int node = mbase + quad * 4 + reg;
        ((unsigned*)(hdst + (size_t)node * 64))[j0] = (unsigned)wpk[reg];
    }
}

// ---- aggX[p] for the 8192 (graph,b) prop pairs only ----
__global__ __launch_bounds__(256) void aggx_kernel(
    const int* __restrict__ prop0, const int* __restrict__ prop1,
    const int* __restrict__ rowptr, const int* __restrict__ csr,
    const unsigned char* __restrict__ hb8, unsigned short* __restrict__ aggX) {
    const int t = threadIdx.x;
    const int p = blockIdx.x * 64 + (t >> 2);
    const int c = t & 3;
    const int node = (p < BT) ? prop0[p] : NN + prop1[p - BT];
    const int start = rowptr[node];
    const int end = (node + 1 < NN2) ? rowptr[node + 1] : 2 * NE;
    float acc[16];
#pragma unroll
    for (int j = 0; j < 16; ++j) acc[j] = 0.f;
    for (int e = start; e < end; ++e) {
        const uint4 u = *(const uint4*)(hb8 + (size_t)csr[e] * 64 + c * 16);
        acc16(acc, u);
    }
    uint4 o0, o1;
    o0.x = packb(acc[0], acc[1]);
    o0.y = packb(acc[2], acc[3]);
    o0.z = packb(acc[4], acc[5]);
    o0.w = packb(acc[6], acc[7]);
    o1.x = packb(acc[8], acc[9]);
    o1.y = packb(acc[10], acc[11]);
    o1.z = packb(acc[12], acc[13]);
    o1.w = packb(acc[14], acc[15]);
    *(uint4*)(aggX + p * 64 + c * 16) = o0;
    *(uint4*)(aggX + p * 64 + c * 16 + 8) = o1;
}

// ---- Last-timestep GRU over the 8192 prop pairs only; writes X (fp32) directly. ----
__global__ __launch_bounds__(256) void grux_kernel(
    const int* __restrict__ prop0, const int* __restrict__ prop1,
    const unsigned char* __restrict__ hb8, const unsigned short* __restrict__ aggX,
    const float* __restrict__ deg, const unsigned short* __restrict__ Wpk,
    const float* __restrict__ bf, const float* __restrict__ bih, const float* __restrict__ bhh,
    float* __restrict__ X) {
    extern __shared__ unsigned short ldsW[];  // 64 KB
    {
        const uint4* src = (const uint4*)Wpk;
        uint4* dst = (uint4*)ldsW;
        for (int i = threadIdx.x; i < 4096; i += 256) dst[i] = src[i];
    }
    __syncthreads();
    const int lane = threadIdx.x & 63;
    const int j0 = lane & 15, quad = lane >> 4;
    const int q8 = quad * 8;
    float cr[4], cz[4], cig[4], chg[4], vbfr[4], vbfz[4], vbfg[4];
#pragma unroll
    for (int c4 = 0; c4 < 4; ++c4) {
        const int col = c4 * 16 + j0;
        cr[c4] = bih[col] + bhh[col];
        cz[c4] = bih[64 + col] + bhh[64 + col];
        cig[c4] = bih[128 + col];
        chg[c4] = bhh[128 + col];
        vbfr[c4] = bf[col];
        vbfz[c4] = bf[64 + col];
        vbfg[c4] = bf[128 + col];
    }
    const short8* ldsW8 = (const short8*)ldsW;
    const int gw = blockIdx.x * 4 + (threadIdx.x >> 6);  // 0..255, tile of 32 pairs

    auto mapnode = [&](int p) { return (p < BT) ? prop0[p] : NN + prop1[p - BT]; };

    auto epilogue = [&](const f32x4(&acc)[16], int pb) {
#pragma unroll
        for (int reg = 0; reg < 4; ++reg) {
            const int p = pb + reg;
            const int node = mapnode(p);
            const float dg = deg[node];
            const unsigned hu = *(const unsigned*)(hb8 + (size_t)node * 64 + j0 * 4);
            const f32x2 h01 = __builtin_amdgcn_cvt_pk_f32_fp8(hu, false);
            const f32x2 h23 = __builtin_amdgcn_cvt_pk_f32_fp8(hu, true);
            const float holdf[4] = {h01.x, h01.y, h23.x, h23.y};
            const int b = p & (BT - 1), g = p >> 12;
            float* xr = X + b * 128 + g * 64;
#pragma unroll
            for (int c4 = 0; c4 < 4; ++c4) {
                const int col = c4 * 16 + j0;
                const float rv = sig1(acc[c4][reg] + cr[c4] + dg * vbfr[c4]);
                const float zv = sig1(acc[4 + c4][reg] + cz[c4] + dg * vbfz[c4]);
                const float gi = acc[8 + c4][reg] + cig[c4] + dg * vbfg[c4];
                const float gh = acc[12 + c4][reg] + chg[c4];
                const float nv = tanh1(fmaf(rv, gh, gi));
                xr[col] = (1.f - zv) * nv + zv * holdf[c4];
            }
        }
    };

    const int mbase = gw * 32;
    const int p0 = mbase + j0, p1 = p0 + 16;
    const int node0 = mapnode(p0), node1 = mapnode(p1);
    short8 a[4], b[4];
    a[0] = *(const short8*)(aggX + p0 * 64 + q8);
    a[1] = *(const short8*)(aggX + p0 * 64 + 32 + q8);
    a[2] = f8frag(*(const uint2*)(hb8 + (size_t)node0 * 64 + q8));
    a[3] = f8frag(*(const uint2*)(hb8 + (size_t)node0 * 64 + 32 + q8));
    b[0] = *(const short8*)(aggX + p1 * 64 + q8);
    b[1] = *(const short8*)(aggX + p1 * 64 + 32 + q8);
    b[2] = f8frag(*(const uint2*)(hb8 + (size_t)node1 * 64 + q8));
    b[3] = f8frag(*(const uint2*)(hb8 + (size_t)node1 * 64 + 32 + q8));
    f32x4 acc0[16], acc1[16];
#pragma unroll
    for (int i = 0; i < 16; ++i) {
        acc0[i] = (f32x4){0.f, 0.f, 0.f, 0.f};
        acc1[i] = (f32x4){0.f, 0.f, 0.f, 0.f};
    }
#pragma unroll
    for (int nt = 0; nt < 16; ++nt) {
#pragma unroll
        for (int kk = 0; kk < 4; ++kk) {
            const short8 w = ldsW8[(nt * 4 + kk) * 64 + lane];
            acc0[nt] = __builtin_amdgcn_mfma_f32_16x16x32_bf16(a[kk], w, acc0[nt], 0, 0, 0);
            acc1[nt] = __builtin_amdgcn_mfma_f32_16x16x32_bf16(b[kk], w, acc1[nt], 0, 0, 0);
        }
    }
    epilogue(acc0, mbase + quad * 4);
    epilogue(acc1, mbase + 16 + quad * 4);
}

// ---- hidden = relu(X@W1+b1); z = hidden@W2+b2; out[b]=sigmoid(z); zbuf[b]=z ----
__global__ __launch_bounds__(256) void mlp_kernel(
    const float* __restrict__ X, const float* __restrict__ W1, const float* __restrict__ b1,
    const float* __restrict__ W2, const float* __restrict__ b2,
    float* __restrict__ out, float* __restrict__ zbuf) {
    const int b = blockIdx.x * 4 + (threadIdx.x >> 6);
    const int j = threadIdx.x & 63;
    const float* x = X + b * 128;
    float acc = b1[j];
#pragma unroll 4
    for (int k = 0; k < 128; ++k) acc = fmaf(x[k], W1[k * 64 + j], acc);
    float v = fmaxf(acc, 0.f) * W2[j];
#pragma unroll
    for (int off = 32; off > 0; off >>= 1) v += __shfl_down(v, off);
    if (j == 0) {
        const float z = v + b2[0];
        out[b] = 1.f / (1.f + expf(-z));
        zbuf[b] = z;
    }
}

// ---- loss = -mean(y*logsig(z) + (1-y)*logsig(-z)) -> out[BT] ----
__global__ __launch_bounds__(256) void loss_kernel(
    const float* __restrict__ zbuf, const int* __restrict__ labels, float* __restrict__ out) {
    __shared__ float red[256];
    const int t = threadIdx.x;
    float s = 0.f;
    for (int i = t; i < BT; i += 256) {
        const float z = zbuf[i];
        const float y = (float)labels[i];
        const float lsp = (z >= 0.f) ? -log1pf(expf(-z)) : (z - log1pf(expf(z)));
        const float lsn = lsp - z;
        s += y * lsp + (1.f - y) * lsn;
    }
    red[t] = s;
    __syncthreads();
    for (int off = 128; off > 0; off >>= 1) {
        if (t < off) red[t] += red[t + off];
        __syncthreads();
    }
    if (t == 0) out[BT] = -red[0] / (float)BT;
}

extern "C" void kernel_launch(void* const* d_in, const int* in_sizes, int n_in,
                              void* d_out, int out_size, void* d_ws, size_t ws_size,
                              hipStream_t stream) {
    char* ws = (char*)d_ws;
    // hb8B aliases the old aggb region (aggb no longer exists).
    unsigned char* hb8B = (unsigned char*)(ws);               // 12,800,000 B
    unsigned char* hb8A = (unsigned char*)(ws + 25600000);    // 12,800,000 B
    float* deg = (float*)(ws + 38400000);                     // 800,000 B
    float* Wf = (float*)(ws + 39200000);                      // 98,304 B
    float* bf = (float*)(ws + 39298304);                      // 1,536 B
    int* rowptr = (int*)(ws + 39299840);                      // 800,000 B (compact)
    int* csr = (int*)(ws + 40099840);                         // 9,600,000 B
    int* bsum = (int*)(ws + 49699840);                        // 1,024 B
    unsigned short* Wpk = (unsigned short*)(ws + 49700864);   // 131,072 B
    unsigned short* aggX = (unsigned short*)(ws + 49831936);  // 1,048,576 B
    // rank + padded hcount alias the hb8A region (dead until agru step 0; both are
    // fully consumed by fill/scan3, which run before agru).
    int* rank = (int*)(ws + 25600000);                        // 9,600,000 B (alias hb8A)
    int* hcount = (int*)(ws + 35200000);                      // 3,200,000 B (alias hb8A tail)
    // X/zbuf alias hb8B region (dead when grux runs; grux reads hb8A + aggX only).
    float* X = (float*)(ws);
    float* zbuf = (float*)(ws + 2097152);
    float* out = (float*)d_out;

    const float* emb_table = (const float*)d_in[7];
    const float* Wp = (const float*)d_in[8];
    const float* bp = (const float*)d_in[9];
    const int* prop0 = (const int*)d_in[4];
    const int* prop1 = (const int*)d_in[5];

    fusew_kernel<<<16, 256, 65536, stream>>>(
        (const float*)d_in[10], (const float*)d_in[12], (const float*)d_in[11],
        (const float*)d_in[16], (const float*)d_in[18], (const float*)d_in[17], Wf, bf);
    wpack_kernel<<<128, 64, 0, stream>>>(Wf, (const float*)d_in[13], (const float*)d_in[19], Wpk);

    // ---- block-level fused hist + embed (padded counters) ----
    hipMemsetAsync(hcount, 0, (size_t)NN2 * 16, stream);
    histemb_kernel<<<NN2 / 16, 256, 0, stream>>>(
        (const int*)d_in[2], (const int*)d_in[3], hcount, rank,
        (const int*)d_in[0], (const int*)d_in[1], emb_table, Wp, bp, hb8B);
    scan1_kernel<<<SCAN_B, 256, 0, stream>>>(hcount, bsum);
    scan2_kernel<<<1, 256, 0, stream>>>(bsum);
    scan3_kernel<<<SCAN_B, 256, 0, stream>>>(hcount, rowptr, bsum, deg);
    fill_kernel<<<2 * NE / 256, 256, 0, stream>>>((const int*)d_in[2], (const int*)d_in[3], rowptr,
                                                  rank, csr);

    // ---- 5 fused agg+GRU steps (l0:ts0-2, l1:ts0-1), ping-pong B->A->B->A->B->A ----
    for (int s = 0; s < 5; ++s) {
        const int l = (s < 3) ? 0 : 1;
        const unsigned char* src = (s & 1) ? hb8A : hb8B;
        unsigned char* dst = (s & 1) ? hb8B : hb8A;
        const float* bih = (const float*)d_in[14 + 6 * l];
        const float* bhh = (const float*)d_in[15 + 6 * l];
        agru_kernel<<<NN2 / 64, 256, 8192, stream>>>(
            src, dst, rowptr, csr, deg, Wpk + l * 32768, bf + l * 192, bih, bhh);
    }

    // ---- last timestep (l=1, ts=2), pruned to the 8192 prop pairs; state is in hb8A ----
    {
        const float* bih = (const float*)d_in[20];
        const float* bhh = (const float*)d_in[21];
        aggx_kernel<<<2 * BT / 64, 256, 0, stream>>>(prop0, prop1, rowptr, csr, hb8A, aggX);
        grux_kernel<<<64, 256, 65536, stream>>>(prop0, prop1, hb8A, aggX, deg, Wpk + 32768,
                                                bf + 192, bih, bhh, X);
    }

    mlp_kernel<<<BT / 4, 256, 0, stream>>>(X, (const float*)d_in[22], (const float*)d_in[23],
                                           (const float*)d_in[24], (const float*)d_in[25], out, zbuf);
    loss_kernel<<<1, 256, 0, stream>>>(zbuf, (const int*)d_in[6], out);
}

// Round 14
// 720.099 us; speedup vs baseline: 1.1136x; 1.0667x over previous
//
#include <hip/hip_runtime.h>
#include <math.h>

#define NN 100000
#define NN2 200000
#define NE 1200000
#define EMBD 100
#define HD 64
#define BT 4096
#define SCAN_B 196  // 196 * 1024 >= NN2

typedef __attribute__((ext_vector_type(8))) short short8;  // 8 bf16 (4 VGPRs)
typedef __attribute__((ext_vector_type(4))) float f32x4;   // MFMA C/D
typedef __attribute__((ext_vector_type(2))) float f32x2;   // fp8 pk-cvt result

__device__ __forceinline__ float sig1(float x) { return 1.f / (1.f + __expf(-x)); }
__device__ __forceinline__ float tanh1(float x) {
    x = fminf(fmaxf(x, -15.f), 15.f);
    float e = __expf(2.f * x);
    return (e - 1.f) / (e + 1.f);
}
__device__ __forceinline__ unsigned short f2b(float f) {
    unsigned u = __float_as_uint(f);
    u += 0x7fffu + ((u >> 16) & 1u);
    return (unsigned short)(u >> 16);
}
__device__ __forceinline__ unsigned short hi16(float f) {  // exact for fp8-sourced values
    return (unsigned short)(__float_as_uint(f) >> 16);
}
__device__ __forceinline__ unsigned packb(float lo, float hi) {
    return (unsigned)f2b(lo) | ((unsigned)f2b(hi) << 16);
}
// PERMUTED row layout for hb8 (fp8 state) and agg rows: position p holds feature
// (p&3)*16 + (p>>2); feature f lives at p = 4*(f&15) + (f>>4). Baked into wpack.
__device__ __forceinline__ unsigned pk8(float a, float b, float c, float d) {
    int w = 0;
    w = __builtin_amdgcn_cvt_pk_fp8_f32(a, b, w, false);
    w = __builtin_amdgcn_cvt_pk_fp8_f32(c, d, w, true);
    return (unsigned)w;
}
// 8 fp8 bytes -> 8 bf16 (exact: every e4m3 value is bf16-representable)
__device__ __forceinline__ short8 f8frag(uint2 u) {
    const f32x2 a0 = __builtin_amdgcn_cvt_pk_f32_fp8(u.x, false);
    const f32x2 a1 = __builtin_amdgcn_cvt_pk_f32_fp8(u.x, true);
    const f32x2 a2 = __builtin_amdgcn_cvt_pk_f32_fp8(u.y, false);
    const f32x2 a3 = __builtin_amdgcn_cvt_pk_f32_fp8(u.y, true);
    short8 r;
    r[0] = (short)hi16(a0.x); r[1] = (short)hi16(a0.y);
    r[2] = (short)hi16(a1.x); r[3] = (short)hi16(a1.y);
    r[4] = (short)hi16(a2.x); r[5] = (short)hi16(a2.y);
    r[6] = (short)hi16(a3.x); r[7] = (short)hi16(a3.y);
    return r;
}
// accumulate 16 fp8 features (one uint4) into acc[0..15], fp32, in-order
__device__ __forceinline__ void acc16(float* acc, uint4 u) {
    const f32x2 a0 = __builtin_amdgcn_cvt_pk_f32_fp8(u.x, false);
    const f32x2 a1 = __builtin_amdgcn_cvt_pk_f32_fp8(u.x, true);
    const f32x2 a2 = __builtin_amdgcn_cvt_pk_f32_fp8(u.y, false);
    const f32x2 a3 = __builtin_amdgcn_cvt_pk_f32_fp8(u.y, true);
    const f32x2 a4 = __builtin_amdgcn_cvt_pk_f32_fp8(u.z, false);
    const f32x2 a5 = __builtin_amdgcn_cvt_pk_f32_fp8(u.z, true);
    const f32x2 a6 = __builtin_amdgcn_cvt_pk_f32_fp8(u.w, false);
    const f32x2 a7 = __builtin_amdgcn_cvt_pk_f32_fp8(u.w, true);
    acc[0] += a0.x; acc[1] += a0.y; acc[2] += a1.x; acc[3] += a1.y;
    acc[4] += a2.x; acc[5] += a2.y; acc[6] += a3.x; acc[7] += a3.y;
    acc[8] += a4.x; acc[9] += a4.y; acc[10] += a5.x; acc[11] += a5.y;
    acc[12] += a6.x; acc[13] += a6.y; acc[14] += a7.x; acc[15] += a7.y;
}

// ---- precompute Wf[l] = Wm[l] @ Wih[l] (64x192), bf[l] = bm[l] @ Wih[l] (192) ----
__global__ __launch_bounds__(256) void fusew_kernel(
    const float* __restrict__ Wm0, const float* __restrict__ Wih0, const float* __restrict__ bm0,
    const float* __restrict__ Wm1, const float* __restrict__ Wih1, const float* __restrict__ bm1,
    float* __restrict__ Wf, float* __restrict__ bf) {
    extern __shared__ float lds[];
    float* wm_s = lds;          // 4096
    float* wih_s = lds + 4096;  // 12288
    const int l = blockIdx.x >> 3, slice = blockIdx.x & 7;
    const float* Wm = l ? Wm1 : Wm0;
    const float* Wih = l ? Wih1 : Wih0;
    const float* bm = l ? bm1 : bm0;
    for (int i = threadIdx.x; i < 4096; i += 256) wm_s[i] = Wm[i];
    for (int i = threadIdx.x; i < 12288; i += 256) wih_s[i] = Wih[i];
    __syncthreads();
    float* Wfl = Wf + l * 12288;
    float* bfl = bf + l * 192;
    const int o0 = slice * 1536;
    for (int o = o0 + threadIdx.x; o < o0 + 1536; o += 256) {
        int r = o / 192, c = o % 192;
        float s = 0.f;
        for (int k = 0; k < 64; ++k) s = fmaf(wm_s[r * 64 + k], wih_s[k * 192 + c], s);
        Wfl[o] = s;
    }
    const int c0 = slice * 24;
    for (int c = c0 + threadIdx.x; c < c0 + 24; c += 256) {
        float s = 0.f;
        for (int k = 0; k < 64; ++k) s = fmaf(bm[k], wih_s[k * 192 + c], s);
        bfl[c] = s;
    }
}

// ---- pack W' (128x256) into MFMA B-fragment order, bf16. Both halves permuted rows. ----
__global__ __launch_bounds__(64) void wpack_kernel(
    const float* __restrict__ Wf, const float* __restrict__ Whh0, const float* __restrict__ Whh1,
    unsigned short* __restrict__ Wpk) {
    const int b = blockIdx.x;  // 0..127
    const int l = b >> 6, frag = b & 63;
    const int nt = frag >> 2, kk = frag & 3;
    const int lane = threadIdx.x;
    const int n = nt * 16 + (lane & 15);
    const int g = n >> 6, j = n & 63;
    const int k0 = kk * 32 + (lane >> 4) * 8;
    const float* wf = Wf + l * 12288;
    const float* whh = l ? Whh1 : Whh0;
    unsigned short o[8];
#pragma unroll
    for (int jj = 0; jj < 8; ++jj) {
        const int k = k0 + jj;
        float v = 0.f;
        if (k < 64) {
            const int kp = (k & 3) * 16 + (k >> 2);
            if (g == 0) v = wf[kp * 192 + j];
            else if (g == 1) v = wf[kp * 192 + 64 + j];
            else if (g == 2) v = wf[kp * 192 + 128 + j];
        } else {
            const int kp = ((k - 64) & 3) * 16 + ((k - 64) >> 2);
            if (g == 0) v = whh[kp * 192 + j];
            else if (g == 1) v = whh[kp * 192 + 64 + j];
            else if (g == 3) v = whh[kp * 192 + 128 + j];
        }
        o[jj] = f2b(v);
    }
    *(uint4*)(Wpk + ((size_t)(l * 64 + frag) * 64 + lane) * 8) = *(const uint4*)o;
}

// ---- BLOCK-LEVEL fused hist + embed, PADDED counters. (R10: padding = null result,
// atomic wall is per-op fabric throughput; kept since harmless.)
// Atomic issued FIRST, rank stored LAST — embed body runs in the atomic shadow.
__global__ __launch_bounds__(256) void histemb_kernel(
    const int* __restrict__ adj0, const int* __restrict__ adj1, int* __restrict__ hcount,
    int* __restrict__ rank,
    const int* __restrict__ ind0, const int* __restrict__ ind1, const float* __restrict__ emb,
    const float* __restrict__ Wp, const float* __restrict__ bp, unsigned char* __restrict__ hb8) {
    __shared__ float et[4][EMBD][4];  // [wave][k][node]
    const int tid = threadIdx.x;

    // ---- hist role: issue the returning atomic now, consume at the very end ----
    int rsave = 0, esave = -1;
    if (tid < 192) {
        const int e = blockIdx.x * 192 + tid;
        const int tgt = (e < NE) ? adj0[2 * e + 1] : adj1[2 * (e - NE) + 1] + NN;
        rsave = atomicAdd(&hcount[tgt << 2], 1);
        esave = e;
    }

    // ---- embed role (unchanged body) ----
    const int w = tid >> 6;
    const int l = tid & 63;
    const int nodeBase = blockIdx.x * 16 + w * 4;  // global node id (graph-pure per block)
    for (int f = l; f < 100; f += 64) {
        const int n = f / 25, c = f % 25;
        const int gn = nodeBase + n;
        const int idx = (gn < NN) ? ind0[gn] : ind1[gn - NN];
        const float4 v = *(const float4*)(emb + (size_t)idx * EMBD + c * 4);
        et[w][c * 4 + 0][n] = v.x;
        et[w][c * 4 + 1][n] = v.y;
        et[w][c * 4 + 2][n] = v.z;
        et[w][c * 4 + 3][n] = v.w;
    }
    __syncthreads();
    float acc[4];
    acc[0] = bp[l]; acc[1] = acc[0]; acc[2] = acc[0]; acc[3] = acc[0];
#pragma unroll 5
    for (int k = 0; k < EMBD; ++k) {
        const float wv = Wp[k * 64 + l];
        const float4 ev = *(const float4*)&et[w][k][0];
        acc[0] = fmaf(ev.x, wv, acc[0]);
        acc[1] = fmaf(ev.y, wv, acc[1]);
        acc[2] = fmaf(ev.z, wv, acc[2]);
        acc[3] = fmaf(ev.w, wv, acc[3]);
    }
#pragma unroll
    for (int n = 0; n < 4; ++n) {
        const float v0 = __shfl(acc[n], l & 15);
        const float v1 = __shfl(acc[n], (l & 15) + 16);
        const float v2 = __shfl(acc[n], (l & 15) + 32);
        const float v3 = __shfl(acc[n], (l & 15) + 48);
        if (l < 16) ((unsigned*)(hb8 + (size_t)(nodeBase + n) * 64))[l] = pk8(v0, v1, v2, v3);
    }

    // ---- hist role epilogue: consume the atomic result ----
    if (esave >= 0) rank[esave] = rsave;
}

__global__ __launch_bounds__(256) void scan1_kernel(const int* __restrict__ hcount, int* __restrict__ bsum) {
    __shared__ int red[256];
    const int t = threadIdx.x, b = blockIdx.x;
    const int base = b * 1024;
    int s = 0;
    for (int i = t; i < 1024; i += 256) {
        const int idx = base + i;
        s += (idx < NN2) ? hcount[idx << 2] : 0;
    }
    red[t] = s;
    __syncthreads();
    for (int off = 128; off > 0; off >>= 1) {
        if (t < off) red[t] += red[t + off];
        __syncthreads();
    }
    if (t == 0) bsum[b] = red[0];
}

__global__ __launch_bounds__(256) void scan2_kernel(int* __restrict__ bsum) {
    __shared__ int s[256];
    const int t = threadIdx.x;
    const int v = (t < SCAN_B) ? bsum[t] : 0;
    s[t] = v;
    __syncthreads();
    for (int off = 1; off < 256; off <<= 1) {
        const int x = (t >= off) ? s[t - off] : 0;
        __syncthreads();
        s[t] += x;
        __syncthreads();
    }
    if (t < SCAN_B) bsum[t] = s[t] - v;  // exclusive
}

// ---- reads padded hcount, writes COMPACT exclusive-start rowptr + deg ----
__global__ __launch_bounds__(256) void scan3_kernel(const int* __restrict__ hcount,
                                                    int* __restrict__ rowptr,
                                                    const int* __restrict__ bsum,
                                                    float* __restrict__ deg) {
    __shared__ int red[256];
    const int t = threadIdx.x, b = blockIdx.x;
    const int i0 = b * 1024 + t * 4;
    int v[4];
#pragma unroll
    for (int j = 0; j < 4; ++j) v[j] = (i0 + j < NN2) ? hcount[(i0 + j) << 2] : 0;
    const int ts = v[0] + v[1] + v[2] + v[3];
    red[t] = ts;
    __syncthreads();
    for (int off = 1; off < 256; off <<= 1) {
        const int x = (t >= off) ? red[t - off] : 0;
        __syncthreads();
        red[t] += x;
        __syncthreads();
    }
    int pre = bsum[b] + red[t] - ts;
#pragma unroll
    for (int j = 0; j < 4; ++j) {
        if (i0 + j < NN2) {
            rowptr[i0 + j] = pre;  // EXCLUSIVE start (compact)
            deg[i0 + j] = (float)v[j];
            pre += v[j];
        }
    }
}

// ---- ATOMIC-FREE fill: slot = rowptr[tgt] (exclusive base) + rank[e]. ----
__global__ __launch_bounds__(256) void fill_kernel(
    const int* __restrict__ adj0, const int* __restrict__ adj1,
    const int* __restrict__ rowptr, const int* __restrict__ rank, int* __restrict__ csr) {
    const int e = blockIdx.x * 256 + threadIdx.x;
    int2 st;
    int off;
    if (e < NE) {
        st = ((const int2*)adj0)[e];
        off = 0;
    } else {
        st = ((const int2*)adj1)[e - NE];
        off = NN;
    }
    const int tgt = st.y + off;
    csr[rowptr[tgt] + rank[e]] = st.x + off;
}

// ---- FUSED aggregate + MFMA GRU, ping-pong state. Block = 64 nodes, 4 waves,
// ONE 16-row M-tile per wave. Gather: 4 thr/node, 4-edge unroll, swizzled LDS rows.
// Wave w gathers nodes [16w,16w+16) and MFMAs exactly those rows: no barrier needed.
// (R11 csr-staging and R13 c4-split both REGRESSED vs this config — kept verbatim.)
__global__ __launch_bounds__(256) void agru_kernel(
    const unsigned char* __restrict__ hsrc, unsigned char* __restrict__ hdst,
    const int* __restrict__ rowptr, const int* __restrict__ csr,
    const float* __restrict__ deg, const unsigned short* __restrict__ Wpk,
    const float* __restrict__ bf, const float* __restrict__ bih, const float* __restrict__ bhh) {
    extern __shared__ unsigned short ldsag[];  // 8192 B: 64-row A-tile
    char* ldsA = (char*)ldsag;
    const int tid = threadIdx.x;

    // ---- phase 1: gather (4 threads/node, 16 features each) ----
    {
        const int nl = tid >> 2;  // local node 0..63
        const int c = tid & 3;    // 16-feature (16 B fp8) chunk
        const int node = blockIdx.x * 64 + nl;
        const int start = rowptr[node];
        const int end = (node + 1 < NN2) ? rowptr[node + 1] : 2 * NE;
        float acc[16];
#pragma unroll
        for (int j = 0; j < 16; ++j) acc[j] = 0.f;
        int e = start;
        for (; e + 3 < end; e += 4) {
            int s[4];
            uint4 u[4];
#pragma unroll
            for (int q = 0; q < 4; ++q) s[q] = csr[e + q];
#pragma unroll
            for (int q = 0; q < 4; ++q) u[q] = *(const uint4*)(hsrc + (size_t)s[q] * 64 + c * 16);
#pragma unroll
            for (int q = 0; q < 4; ++q) acc16(acc, u[q]);
        }
        for (; e < end; ++e) {
            const uint4 u = *(const uint4*)(hsrc + (size_t)csr[e] * 64 + c * 16);
            acc16(acc, u);
        }
        uint4 o0, o1;
        o0.x = packb(acc[0], acc[1]);
        o0.y = packb(acc[2], acc[3]);
        o0.z = packb(acc[4], acc[5]);
        o0.w = packb(acc[6], acc[7]);
        o1.x = packb(acc[8], acc[9]);
        o1.y = packb(acc[10], acc[11]);
        o1.z = packb(acc[12], acc[13]);
        o1.w = packb(acc[14], acc[15]);
        const int rowb = nl * 128 + c * 32;  // byte base within A-tile
        const int swz = (nl & 7) << 4;       // bank swizzle (16B-slot XOR within row)
        *(uint4*)(ldsA + ((rowb + 0) ^ swz)) = o0;
        *(uint4*)(ldsA + ((rowb + 16) ^ swz)) = o1;
    }

    // ---- phase 2: MFMA GRU (wave-local rows; no block barrier needed) ----
    const int lane = tid & 63;
    const int w = tid >> 6;
    const int j0 = lane & 15, quad = lane >> 4;
    const int q8 = quad * 8;
    const int mbase = blockIdx.x * 64 + w * 16;

    float cr[4], cz[4], cig[4], chg[4], vbfr[4], vbfz[4], vbfg[4];
#pragma unroll
    for (int c4 = 0; c4 < 4; ++c4) {
        const int col = c4 * 16 + j0;
        cr[c4] = bih[col] + bhh[col];
        cz[c4] = bih[64 + col] + bhh[64 + col];
        cig[c4] = bih[128 + col];
        chg[c4] = bhh[128 + col];
        vbfr[c4] = bf[col];
        vbfz[c4] = bf[64 + col];
        vbfg[c4] = bf[128 + col];
    }
    const short8* Wg8 = (const short8*)Wpk;  // global, L2-resident
    const int lr = w * 16 + j0;              // local A-row 0..63
    const int node0 = mbase + j0;
    auto ldA = [&](int half) -> short8 {
        const int byteoff = (lr * 128 + half * 64 + quad * 16) ^ ((lr & 7) << 4);
        return *(const short8*)(ldsA + byteoff);
    };

    short8 a[4];
    a[0] = ldA(0);
    a[1] = ldA(1);
    a[2] = f8frag(*(const uint2*)(hsrc + (size_t)node0 * 64 + q8));
    a[3] = f8frag(*(const uint2*)(hsrc + (size_t)node0 * 64 + 32 + q8));
    f32x4 acc[16];
#pragma unroll
    for (int i = 0; i < 16; ++i) acc[i] = (f32x4){0.f, 0.f, 0.f, 0.f};
#pragma unroll
    for (int nt = 0; nt < 16; ++nt) {
#pragma unroll
        for (int kk = 0; kk < 4; ++kk) {
            const short8 wv = Wg8[(nt * 4 + kk) * 64 + lane];
            acc[nt] = __builtin_amdgcn_mfma_f32_16x16x32_bf16(a[kk], wv, acc[nt], 0, 0, 0);
        }
    }

    // epilogue: rows mbase+quad*4 .. +4
#pragma unroll
    for (int reg = 0; reg < 4; ++reg) {
        const int node = mbase + quad * 4 + reg;
        const float dg = deg[node];
        const unsigned hu = *(const unsigned*)(hsrc + (size_t)node * 64 + j0 * 4);
        const f32x2 h01 = __builtin_amdgcn_cvt_pk_f32_fp8(hu, false);
        const f32x2 h23 = __builtin_amdgcn_cvt_pk_f32_fp8(hu, true);
        const float holdf[4] = {h01.x, h01.y, h23.x, h23.y};
        float hn[4];
#pragma unroll
        for (int c4 = 0; c4 < 4; ++c4) {
            const float rv = sig1(acc[c4][reg] + cr[c4] + dg * vbfr[c4]);
            const float zv = sig1(acc[4 + c4][reg] + cz[c4] + dg * vbfz[c4]);
            const float gi = acc[8 + c4][reg] + cig[c4] + dg * vbfg[c4];
            const float gh = acc[12 + c4][reg] + chg[c4];
            const float nv = tanh1(fmaf(rv, gh, gi));
            hn[c4] = (1.f - zv) * nv + zv * holdf[c4];
        }
        ((unsigned*)(hdst + (size_t)node * 64))[j0] = pk8(hn[0], hn[1], hn[2], hn[3]);
    }
}

// ---- aggX[p] for the 8192 (graph,b) prop pairs only ----
__global__ __launch_bounds__(256) void aggx_kernel(
    const int* __restrict__ prop0, const int* __restrict__ prop1,
    const int* __restrict__ rowptr, const int* __restrict__ csr,
    const unsigned char* __restrict__ hb8, unsigned short* __restrict__ aggX) {
    const int t = threadIdx.x;
    const int p = blockIdx.x * 64 + (t >> 2);
    const int c = t & 3;
    const int node = (p < BT) ? prop0[p] : NN + prop1[p - BT];
    const int start = rowptr[node];
    const int end = (node + 1 < NN2) ? rowptr[node + 1] : 2 * NE;
    float acc[16];
#pragma unroll
    for (int j = 0; j < 16; ++j) acc[j] = 0.f;
    for (int e = start; e < end; ++e) {
        const uint4 u = *(const uint4*)(hb8 + (size_t)csr[e] * 64 + c * 16);
        acc16(acc, u);
    }
    uint4 o0, o1;
    o0.x = packb(acc[0], acc[1]);
    o0.y = packb(acc[2], acc[3]);
    o0.z = packb(acc[4], acc[5]);
    o0.w = packb(acc[6], acc[7]);
    o1.x = packb(acc[8], acc[9]);
    o1.y = packb(acc[10], acc[11]);
    o1.z = packb(acc[12], acc[13]);
    o1.w = packb(acc[14], acc[15]);
    *(uint4*)(aggX + p * 64 + c * 16) = o0;
    *(uint4*)(aggX + p * 64 + c * 16 + 8) = o1;
}

// ---- Last-timestep GRU over the 8192 prop pairs only; writes X (fp32) directly. ----
__global__ __launch_bounds__(256) void grux_kernel(
    const int* __restrict__ prop0, const int* __restrict__ prop1,
    const unsigned char* __restrict__ hb8, const unsigned short* __restrict__ aggX,
    const float* __restrict__ deg, const unsigned short* __restrict__ Wpk,
    const float* __restrict__ bf, const float* __restrict__ bih, const float* __restrict__ bhh,
    float* __restrict__ X) {
    extern __shared__ unsigned short ldsW[];  // 64 KB
    {
        const uint4* src = (const uint4*)Wpk;
        uint4* dst = (uint4*)ldsW;
        for (int i = threadIdx.x; i < 4096; i += 256) dst[i] = src[i];
    }
    __syncthreads();
    const int lane = threadIdx.x & 63;
    const int j0 = lane & 15, quad = lane >> 4;
    const int q8 = quad * 8;
    float cr[4], cz[4], cig[4], chg[4], vbfr[4], vbfz[4], vbfg[4];
#pragma unroll
    for (int c4 = 0; c4 < 4; ++c4) {
        const int col = c4 * 16 + j0;
        cr[c4] = bih[col] + bhh[col];
        cz[c4] = bih[64 + col] + bhh[64 + col];
        cig[c4] = bih[128 + col];
        chg[c4] = bhh[128 + col];
        vbfr[c4] = bf[col];
        vbfz[c4] = bf[64 + col];
        vbfg[c4] = bf[128 + col];
    }
    const short8* ldsW8 = (const short8*)ldsW;
    const int gw = blockIdx.x * 4 + (threadIdx.x >> 6);  // 0..255, tile of 32 pairs

    auto mapnode = [&](int p) { return (p < BT) ? prop0[p] : NN + prop1[p - BT]; };

    auto epilogue = [&](const f32x4(&acc)[16], int pb) {
#pragma unroll
        for (int reg = 0; reg < 4; ++reg) {
            const int p = pb + reg;
            const int node = mapnode(p);
            const float dg = deg[node];
            const unsigned hu = *(const unsigned*)(hb8 + (size_t)node * 64 + j0 * 4);
            const f32x2 h01 = __builtin_amdgcn_cvt_pk_f32_fp8(hu, false);
            const f32x2 h23 = __builtin_amdgcn_cvt_pk_f32_fp8(hu, true);
            const float holdf[4] = {h01.x, h01.y, h23.x, h23.y};
            const int b = p & (BT - 1), g = p >> 12;
            float* xr = X + b * 128 + g * 64;
#pragma unroll
            for (int c4 = 0; c4 < 4; ++c4) {
                const int col = c4 * 16 + j0;
                const float rv = sig1(acc[c4][reg] + cr[c4] + dg * vbfr[c4]);
                const float zv = sig1(acc[4 + c4][reg] + cz[c4] + dg * vbfz[c4]);
                const float gi = acc[8 + c4][reg] + cig[c4] + dg * vbfg[c4];
                const float gh = acc[12 + c4][reg] + chg[c4];
                const float nv = tanh1(fmaf(rv, gh, gi));
                xr[col] = (1.f - zv) * nv + zv * holdf[c4];
            }
        }
    };

    const int mbase = gw * 32;
    const int p0 = mbase + j0, p1 = p0 + 16;
    const int node0 = mapnode(p0), node1 = mapnode(p1);
    short8 a[4], b[4];
    a[0] = *(const short8*)(aggX + p0 * 64 + q8);
    a[1] = *(const short8*)(aggX + p0 * 64 + 32 + q8);
    a[2] = f8frag(*(const uint2*)(hb8 + (size_t)node0 * 64 + q8));
    a[3] = f8frag(*(const uint2*)(hb8 + (size_t)node0 * 64 + 32 + q8));
    b[0] = *(const short8*)(aggX + p1 * 64 + q8);
    b[1] = *(const short8*)(aggX + p1 * 64 + 32 + q8);
    b[2] = f8frag(*(const uint2*)(hb8 + (size_t)node1 * 64 + q8));
    b[3] = f8frag(*(const uint2*)(hb8 + (size_t)node1 * 64 + 32 + q8));
    f32x4 acc0[16], acc1[16];
#pragma unroll
    for (int i = 0; i < 16; ++i) {
        acc0[i] = (f32x4){0.f, 0.f, 0.f, 0.f};
        acc1[i] = (f32x4){0.f, 0.f, 0.f, 0.f};
    }
#pragma unroll
    for (int nt = 0; nt < 16; ++nt) {
#pragma unroll
        for (int kk = 0; kk < 4; ++kk) {
            const short8 w = ldsW8[(nt * 4 + kk) * 64 + lane];
            acc0[nt] = __builtin_amdgcn_mfma_f32_16x16x32_bf16(a[kk], w, acc0[nt], 0, 0, 0);
            acc1[nt] = __builtin_amdgcn_mfma_f32_16x16x32_bf16(b[kk], w, acc1[nt], 0, 0, 0);
        }
    }
    epilogue(acc0, mbase + quad * 4);
    epilogue(acc1, mbase + 16 + quad * 4);
}

// ---- hidden = relu(X@W1+b1); z = hidden@W2+b2; out[b]=sigmoid(z); zbuf[b]=z ----
__global__ __launch_bounds__(256) void mlp_kernel(
    const float* __restrict__ X, const float* __restrict__ W1, const float* __restrict__ b1,
    const float* __restrict__ W2, const float* __restrict__ b2,
    float* __restrict__ out, float* __restrict__ zbuf) {
    const int b = blockIdx.x * 4 + (threadIdx.x >> 6);
    const int j = threadIdx.x & 63;
    const float* x = X + b * 128;
    float acc = b1[j];
#pragma unroll 4
    for (int k = 0; k < 128; ++k) acc = fmaf(x[k], W1[k * 64 + j], acc);
    float v = fmaxf(acc, 0.f) * W2[j];
#pragma unroll
    for (int off = 32; off > 0; off >>= 1) v += __shfl_down(v, off);
    if (j == 0) {
        const float z = v + b2[0];
        out[b] = 1.f / (1.f + expf(-z));
        zbuf[b] = z;
    }
}

// ---- loss = -mean(y*logsig(z) + (1-y)*logsig(-z)) -> out[BT] ----
__global__ __launch_bounds__(256) void loss_kernel(
    const float* __restrict__ zbuf, const int* __restrict__ labels, float* __restrict__ out) {
    __shared__ float red[256];
    const int t = threadIdx.x;
    float s = 0.f;
    for (int i = t; i < BT; i += 256) {
        const float z = zbuf[i];
        const float y = (float)labels[i];
        const float lsp = (z >= 0.f) ? -log1pf(expf(-z)) : (z - log1pf(expf(z)));
        const float lsn = lsp - z;
        s += y * lsp + (1.f - y) * lsn;
    }
    red[t] = s;
    __syncthreads();
    for (int off = 128; off > 0; off >>= 1) {
        if (t < off) red[t] += red[t + off];
        __syncthreads();
    }
    if (t == 0) out[BT] = -red[0] / (float)BT;
}

extern "C" void kernel_launch(void* const* d_in, const int* in_sizes, int n_in,
                              void* d_out, int out_size, void* d_ws, size_t ws_size,
                              hipStream_t stream) {
    char* ws = (char*)d_ws;
    // hb8B aliases the old aggb region (aggb no longer exists).
    unsigned char* hb8B = (unsigned char*)(ws);               // 12,800,000 B
    unsigned char* hb8A = (unsigned char*)(ws + 25600000);    // 12,800,000 B
    float* deg = (float*)(ws + 38400000);                     // 800,000 B
    float* Wf = (float*)(ws + 39200000);                      // 98,304 B
    float* bf = (float*)(ws + 39298304);                      // 1,536 B
    int* rowptr = (int*)(ws + 39299840);                      // 800,000 B (compact)
    int* csr = (int*)(ws + 40099840);                         // 9,600,000 B
    int* bsum = (int*)(ws + 49699840);                        // 1,024 B
    unsigned short* Wpk = (unsigned short*)(ws + 49700864);   // 131,072 B
    unsigned short* aggX = (unsigned short*)(ws + 49831936);  // 1,048,576 B
    // rank + padded hcount alias the hb8A region (dead until agru step 0; both are
    // fully consumed by fill/scan3, which run before agru).
    int* rank = (int*)(ws + 25600000);                        // 9,600,000 B (alias hb8A)
    int* hcount = (int*)(ws + 35200000);                      // 3,200,000 B (alias hb8A tail)
    // X/zbuf alias hb8B region (dead when grux runs; grux reads hb8A + aggX only).
    float* X = (float*)(ws);
    float* zbuf = (float*)(ws + 2097152);
    float* out = (float*)d_out;

    const float* emb_table = (const float*)d_in[7];
    const float* Wp = (const float*)d_in[8];
    const float* bp = (const float*)d_in[9];
    const int* prop0 = (const int*)d_in[4];
    const int* prop1 = (const int*)d_in[5];

    fusew_kernel<<<16, 256, 65536, stream>>>(
        (const float*)d_in[10], (const float*)d_in[12], (const float*)d_in[11],
        (const float*)d_in[16], (const float*)d_in[18], (const float*)d_in[17], Wf, bf);
    wpack_kernel<<<128, 64, 0, stream>>>(Wf, (const float*)d_in[13], (const float*)d_in[19], Wpk);

    // ---- block-level fused hist + embed (padded counters) ----
    hipMemsetAsync(hcount, 0, (size_t)NN2 * 16, stream);
    histemb_kernel<<<NN2 / 16, 256, 0, stream>>>(
        (const int*)d_in[2], (const int*)d_in[3], hcount, rank,
        (const int*)d_in[0], (const int*)d_in[1], emb_table, Wp, bp, hb8B);
    scan1_kernel<<<SCAN_B, 256, 0, stream>>>(hcount, bsum);
    scan2_kernel<<<1, 256, 0, stream>>>(bsum);
    scan3_kernel<<<SCAN_B, 256, 0, stream>>>(hcount, rowptr, bsum, deg);
    fill_kernel<<<2 * NE / 256, 256, 0, stream>>>((const int*)d_in[2], (const int*)d_in[3], rowptr,
                                                  rank, csr);

    // ---- 5 fused agg+GRU steps (l0:ts0-2, l1:ts0-1), ping-pong B->A->B->A->B->A ----
    for (int s = 0; s < 5; ++s) {
        const int l = (s < 3) ? 0 : 1;
        const unsigned char* src = (s & 1) ? hb8A : hb8B;
        unsigned char* dst = (s & 1) ? hb8B : hb8A;
        const float* bih = (const float*)d_in[14 + 6 * l];
        const float* bhh = (const float*)d_in[15 + 6 * l];
        agru_kernel<<<NN2 / 64, 256, 8192, stream>>>(
            src, dst, rowptr, csr, deg, Wpk + l * 32768, bf + l * 192, bih, bhh);
    }

    // ---- last timestep (l=1, ts=2), pruned to the 8192 prop pairs; state is in hb8A ----
    {
        const float* bih = (const float*)d_in[20];
        const float* bhh = (const float*)d_in[21];
        aggx_kernel<<<2 * BT / 64, 256, 0, stream>>>(prop0, prop1, rowptr, csr, hb8A, aggX);
        grux_kernel<<<64, 256, 65536, stream>>>(prop0, prop1, hb8A, aggX, deg, Wpk + 32768,
                                                bf + 192, bih, bhh, X);
    }

    mlp_kernel<<<BT / 4, 256, 0, stream>>>(X, (const float*)d_in[22], (const float*)d_in[23],
                                           (const float*)d_in[24], (const float*)d_in[25], out, zbuf);
    loss_kernel<<<1, 256, 0, stream>>>(zbuf, (const int*)d_in[6], out);
}